// Round 8
// baseline (279.954 us; speedup 1.0000x reference)
//
#include <hip/hip_runtime.h>
#include <hip/hip_bf16.h>

#define WAVE 64
typedef unsigned int uint32;
typedef __attribute__((ext_vector_type(8))) short bf16x8;
typedef __attribute__((ext_vector_type(4))) float f32x4;

// ---- bf16 helpers ----
__device__ inline float bf16lo(uint32 u) { return __uint_as_float(u << 16); }
__device__ inline float bf16hi(uint32 u) { return __uint_as_float(u & 0xffff0000u); }
__device__ inline uint32 f2bf(float f) {  // round-to-nearest-even, bits in low 16
    union { float f; uint32 u; } a; a.f = f;
    uint32 u = a.u;
    u += 0x7fffu + ((u >> 16) & 1u);
    return u >> 16;
}
__device__ inline uint32 packbf(float lo, float hi) { return f2bf(lo) | (f2bf(hi) << 16); }
__device__ inline short f2bfs(float f) { return (short)f2bf(f); }

// ---------------- W1/W2 -> fragment-ordered bf16 (+ gcnt zeroing) ----------------
__global__ void convert_w_kernel(const float* __restrict__ W1, const float* __restrict__ W2,
                                 uint32* __restrict__ w1f, uint32* __restrict__ w2f,
                                 int* __restrict__ gcnt) {
    int tid = blockIdx.x * blockDim.x + threadIdx.x;  // 0..20479
    if (tid < 256) gcnt[tid] = 0;
    if (tid < 16384) {
        int w = tid & 3, l = (tid >> 2) & 63, c = (tid >> 8) & 7, kc = tid >> 11;
        int q = l & 15, g = l >> 4;
        int k0 = kc * 32 + g * 8 + 2 * w;
        int n = c * 16 + q;
        w1f[tid] = packbf(W1[k0 * 128 + n], W1[(k0 + 1) * 128 + n]);
    } else if (tid < 16384 + 4096) {
        int t = tid - 16384;
        int w = t & 3, l = (t >> 2) & 63, c = (t >> 8) & 3, kc = t >> 10;
        int q = l & 15, g = l >> 4;
        int k0 = kc * 32 + g * 8 + 2 * w;
        int n = c * 16 + q;
        w2f[t] = packbf(W2[k0 * 64 + n], W2[(k0 + 1) * 64 + n]);
    }
}

// ================= CSR build: two-pass bucket sort =================
#define BIN_TB 1024
#define BIN_EPB 4096
__global__ __launch_bounds__(BIN_TB) void binsort_kernel(const int* __restrict__ src,
                                                         const int* __restrict__ dst,
                                                         int* __restrict__ gcnt,
                                                         uint32* __restrict__ pairs,
                                                         int E, int CAP) {
    __shared__ int hist[256];
    __shared__ int scan[256];
    __shared__ int lstart[256];
    __shared__ int gbase[256];
    __shared__ int lcur[256];
    __shared__ uint32 sp[BIN_EPB];
    __shared__ unsigned char sb[BIN_EPB];
    int tid = threadIdx.x;
    int base = blockIdx.x * BIN_EPB;
    if (tid < 256) hist[tid] = 0;
    __syncthreads();
    int s[4], b[4];
    uint32 pk[4];
    bool v[4];
#pragma unroll
    for (int j = 0; j < 4; ++j) {
        int e = base + tid + j * BIN_TB;
        v[j] = e < E;
        if (v[j]) {
            s[j] = src[e];
            int d = dst[e];
            b[j] = d >> 9;
            pk[j] = (uint32)s[j] | ((uint32)(d & 511) << 17);
            atomicAdd(&hist[b[j]], 1);
        }
    }
    __syncthreads();
    if (tid < 256) scan[tid] = hist[tid];
    __syncthreads();
#pragma unroll
    for (int o = 1; o < 256; o <<= 1) {
        int t = 0;
        if (tid < 256 && tid >= o) t = scan[tid - o];
        __syncthreads();
        if (tid < 256) scan[tid] += t;
        __syncthreads();
    }
    if (tid < 256) {
        int st = scan[tid] - hist[tid];
        lstart[tid] = st;
        lcur[tid] = st;
        gbase[tid] = (hist[tid] > 0) ? (tid * CAP + atomicAdd(&gcnt[tid], hist[tid])) : 0;
    }
    __syncthreads();
#pragma unroll
    for (int j = 0; j < 4; ++j) {
        if (v[j]) {
            int p = atomicAdd(&lcur[b[j]], 1);
            sp[p] = pk[j];
            sb[p] = (unsigned char)b[j];
        }
    }
    __syncthreads();
    int total = scan[255];
    for (int i = tid; i < total; i += BIN_TB) {
        int bb = sb[i];
        pairs[gbase[bb] + (i - lstart[bb])] = sp[i];
    }
}

__global__ __launch_bounds__(512) void bucket_csr_kernel(const uint32* __restrict__ pairs,
                                                         const int* __restrict__ gcnt,
                                                         int* __restrict__ sorted,
                                                         int* __restrict__ rowstart,
                                                         int* __restrict__ rowend,
                                                         float* __restrict__ dinv,
                                                         int N, int CAP) {
    __shared__ int cnt[512];
    __shared__ int incl[512];
    __shared__ int cursor[512];
    extern __shared__ uint32 ssorted[];  // CAP entries
    int b = blockIdx.x;
    int tid = threadIdx.x;
    int ne = gcnt[b];
    if (ne > CAP) ne = CAP;
    const uint32* P = pairs + (size_t)b * CAP;
    cnt[tid] = 0;
    __syncthreads();
    for (int i = tid; i < ne; i += 512) atomicAdd(&cnt[P[i] >> 17], 1);
    __syncthreads();
    int v = cnt[tid];
    incl[tid] = v;
    __syncthreads();
#pragma unroll
    for (int o = 1; o < 512; o <<= 1) {
        int t = (tid >= o) ? incl[tid - o] : 0;
        __syncthreads();
        incl[tid] += t;
        __syncthreads();
    }
    int gbase = b * CAP;
    int node = b * 512 + tid;
    if (node < N) {
        rowstart[node] = gbase + incl[tid] - v;
        rowend[node] = gbase + incl[tid];
        dinv[node] = rsqrtf(1.0f + (float)v);
    }
    cursor[tid] = incl[tid] - v;
    __syncthreads();
    for (int i = tid; i < ne; i += 512) {
        uint32 p = P[i];
        int ln = p >> 17;
        int r = atomicAdd(&cursor[ln], 1);
        ssorted[r] = p & 0x1FFFFu;
    }
    __syncthreads();
    for (int i = tid; i < ne; i += 512) sorted[gbase + i] = (int)ssorted[i];
}

// ---------------- GEMM1 (MFMA): [N,256]fp32 @ W1F -> two planes of bf16 pairs ----------------
// plane0 u32 idx j=[0,32): feats (j, j+64); plane1 j=[32,64) stored at idx j-32.
__global__ __launch_bounds__(256) void gemm1_mfma(const float* __restrict__ x,
                                                  const uint32* __restrict__ w1f,
                                                  const float* __restrict__ dinv,
                                                  uint32* __restrict__ h1a,  // N x 32
                                                  uint32* __restrict__ h1b,  // N x 32
                                                  int N) {
    const bf16x8* Bp = (const bf16x8*)w1f;
    int l = threadIdx.x & 63, w = threadIdx.x >> 6;
    int q = l & 15, g = l >> 4;
    int R = blockIdx.x * 128 + w * 32;
    f32x4 acc[2][8];
#pragma unroll
    for (int rt = 0; rt < 2; ++rt)
#pragma unroll
        for (int c = 0; c < 8; ++c) acc[rt][c] = (f32x4){0.f, 0.f, 0.f, 0.f};

#pragma unroll
    for (int kc = 0; kc < 8; ++kc) {
        bf16x8 b[8];
#pragma unroll
        for (int c = 0; c < 8; ++c) b[c] = Bp[(kc * 8 + c) * 64 + l];
#pragma unroll
        for (int rt = 0; rt < 2; ++rt) {
            int row = R + rt * 16 + q;
            row = row < N ? row : N - 1;
            const float* xr = x + (size_t)row * 256 + kc * 32 + g * 8;
            float4 xa = *(const float4*)xr;
            float4 xb = *(const float4*)(xr + 4);
            bf16x8 a;
            a[0] = f2bfs(xa.x); a[1] = f2bfs(xa.y); a[2] = f2bfs(xa.z); a[3] = f2bfs(xa.w);
            a[4] = f2bfs(xb.x); a[5] = f2bfs(xb.y); a[6] = f2bfs(xb.z); a[7] = f2bfs(xb.w);
#pragma unroll
            for (int c = 0; c < 8; ++c)
                acc[rt][c] = __builtin_amdgcn_mfma_f32_16x16x32_bf16(a, b[c], acc[rt][c], 0, 0, 0);
        }
    }
#pragma unroll
    for (int rt = 0; rt < 2; ++rt)
#pragma unroll
        for (int r = 0; r < 4; ++r) {
            int grow = R + rt * 16 + 4 * g + r;
            if (grow < N) {
                float wd = dinv[grow];
#pragma unroll
                for (int c = 0; c < 4; ++c) {
                    uint32 val = packbf(acc[rt][c][r] * wd, acc[rt][c + 4][r] * wd);
                    uint32* pl = (c < 2) ? h1a : h1b;
                    pl[(size_t)grow * 32 + (c & 1) * 16 + q] = val;
                }
            }
        }
}

// ---------------- layer-1 plane aggregation: uint4 gathers, 8 lanes/edge ----------------
// hp row: 8 uint4 (32 u32). u32 (plane*32+j) = feats (plane*32+j, plane*32+j+64).
// out: bf16 natural pairs, N x 64 u32.
__global__ __launch_bounds__(256) void agg1_plane_kernel(const uint32* __restrict__ hp,
                                                         const float* __restrict__ dinv,
                                                         const int* __restrict__ srt,
                                                         const int* __restrict__ rowstart,
                                                         const int* __restrict__ rowend,
                                                         const float* __restrict__ bias,
                                                         uint32* __restrict__ out,
                                                         int n, int plane) {
    int wid = (int)(((long)blockIdx.x * blockDim.x + threadIdx.x) >> 6);
    int lane = threadIdx.x & 63;
    if (wid >= n) return;
    const uint4* h4 = (const uint4*)hp;  // row = 8 uint4
    int q = lane & 7;
    int g = lane >> 3;
    int start = rowstart[wid];
    int end = rowend[wid];
    float aL0 = 0.f, aL1 = 0.f, aL2 = 0.f, aL3 = 0.f;
    float aH0 = 0.f, aH1 = 0.f, aH2 = 0.f, aH3 = 0.f;
    if (g == 0) {  // self (already dinv-scaled)
        uint4 u = h4[(size_t)wid * 8 + q];
        aL0 = bf16lo(u.x); aH0 = bf16hi(u.x);
        aL1 = bf16lo(u.y); aH1 = bf16hi(u.y);
        aL2 = bf16lo(u.z); aH2 = bf16hi(u.z);
        aL3 = bf16lo(u.w); aH3 = bf16hi(u.w);
    }
    int e = start + g;
    for (; e + 24 < end; e += 32) {  // 4 gathers in flight per 8-lane group
        int s0 = srt[e], s1 = srt[e + 8], s2 = srt[e + 16], s3 = srt[e + 24];
        uint4 u0 = h4[(size_t)s0 * 8 + q];
        uint4 u1 = h4[(size_t)s1 * 8 + q];
        uint4 u2 = h4[(size_t)s2 * 8 + q];
        uint4 u3 = h4[(size_t)s3 * 8 + q];
        aL0 += bf16lo(u0.x); aH0 += bf16hi(u0.x); aL1 += bf16lo(u0.y); aH1 += bf16hi(u0.y);
        aL2 += bf16lo(u0.z); aH2 += bf16hi(u0.z); aL3 += bf16lo(u0.w); aH3 += bf16hi(u0.w);
        aL0 += bf16lo(u1.x); aH0 += bf16hi(u1.x); aL1 += bf16lo(u1.y); aH1 += bf16hi(u1.y);
        aL2 += bf16lo(u1.z); aH2 += bf16hi(u1.z); aL3 += bf16lo(u1.w); aH3 += bf16hi(u1.w);
        aL0 += bf16lo(u2.x); aH0 += bf16hi(u2.x); aL1 += bf16lo(u2.y); aH1 += bf16hi(u2.y);
        aL2 += bf16lo(u2.z); aH2 += bf16hi(u2.z); aL3 += bf16lo(u2.w); aH3 += bf16hi(u2.w);
        aL0 += bf16lo(u3.x); aH0 += bf16hi(u3.x); aL1 += bf16lo(u3.y); aH1 += bf16hi(u3.y);
        aL2 += bf16lo(u3.z); aH2 += bf16hi(u3.z); aL3 += bf16lo(u3.w); aH3 += bf16hi(u3.w);
    }
    for (; e < end; e += 8) {
        uint4 u = h4[(size_t)srt[e] * 8 + q];
        aL0 += bf16lo(u.x); aH0 += bf16hi(u.x); aL1 += bf16lo(u.y); aH1 += bf16hi(u.y);
        aL2 += bf16lo(u.z); aH2 += bf16hi(u.z); aL3 += bf16lo(u.w); aH3 += bf16hi(u.w);
    }
#pragma unroll
    for (int o = 8; o <= 32; o <<= 1) {
        aL0 += __shfl_xor(aL0, o, WAVE); aL1 += __shfl_xor(aL1, o, WAVE);
        aL2 += __shfl_xor(aL2, o, WAVE); aL3 += __shfl_xor(aL3, o, WAVE);
        aH0 += __shfl_xor(aH0, o, WAVE); aH1 += __shfl_xor(aH1, o, WAVE);
        aH2 += __shfl_xor(aH2, o, WAVE); aH3 += __shfl_xor(aH3, o, WAVE);
    }
    float wd = dinv[wid];
    if (g == 0) {  // feats f..f+3, f = plane*32 + 4q
        int f = plane * 32 + 4 * q;
        float4 b = *(const float4*)(bias + f);
        float v0 = fmaxf(fmaf(wd, aL0, b.x), 0.f);
        float v1 = fmaxf(fmaf(wd, aL1, b.y), 0.f);
        float v2 = fmaxf(fmaf(wd, aL2, b.z), 0.f);
        float v3 = fmaxf(fmaf(wd, aL3, b.w), 0.f);
        ((uint2*)(out + (size_t)wid * 64))[plane * 8 + q] = make_uint2(packbf(v0, v1), packbf(v2, v3));
    } else if (g == 1) {  // feats 64+f..64+f+3
        int f = plane * 32 + 4 * q;
        float4 b = *(const float4*)(bias + 64 + f);
        float v0 = fmaxf(fmaf(wd, aH0, b.x), 0.f);
        float v1 = fmaxf(fmaf(wd, aH1, b.y), 0.f);
        float v2 = fmaxf(fmaf(wd, aH2, b.z), 0.f);
        float v3 = fmaxf(fmaf(wd, aH3, b.w), 0.f);
        ((uint2*)(out + (size_t)wid * 64))[16 + plane * 8 + q] = make_uint2(packbf(v0, v1), packbf(v2, v3));
    }
}

// ---------------- GEMM2 (MFMA): [N,128]bf16 @ W2F -> h2s bf16 pairs (f, f+32) ----------------
__global__ __launch_bounds__(256) void gemm2_mfma(const uint32* __restrict__ hin,  // N x 64 bf16-pairs
                                                  const uint32* __restrict__ w2f,
                                                  const float* __restrict__ dinv,
                                                  uint32* __restrict__ hout,  // N x 32
                                                  int N) {
    const bf16x8* Bp = (const bf16x8*)w2f;
    const short* hs = (const short*)hin;
    int l = threadIdx.x & 63, w = threadIdx.x >> 6;
    int q = l & 15, g = l >> 4;
    int R = blockIdx.x * 128 + w * 32;
    f32x4 acc[2][4];
#pragma unroll
    for (int rt = 0; rt < 2; ++rt)
#pragma unroll
        for (int c = 0; c < 4; ++c) acc[rt][c] = (f32x4){0.f, 0.f, 0.f, 0.f};

#pragma unroll
    for (int kc = 0; kc < 4; ++kc) {
        bf16x8 b[4];
#pragma unroll
        for (int c = 0; c < 4; ++c) b[c] = Bp[(kc * 4 + c) * 64 + l];
#pragma unroll
        for (int rt = 0; rt < 2; ++rt) {
            int row = R + rt * 16 + q;
            row = row < N ? row : N - 1;
            bf16x8 a = *(const bf16x8*)(hs + (size_t)row * 128 + kc * 32 + g * 8);
#pragma unroll
            for (int c = 0; c < 4; ++c)
                acc[rt][c] = __builtin_amdgcn_mfma_f32_16x16x32_bf16(a, b[c], acc[rt][c], 0, 0, 0);
        }
    }
#pragma unroll
    for (int rt = 0; rt < 2; ++rt)
#pragma unroll
        for (int r = 0; r < 4; ++r) {
            int grow = R + rt * 16 + 4 * g + r;
            if (grow < N) {
                float wd = dinv[grow];
                uint32* orow = hout + (size_t)grow * 32;
#pragma unroll
                for (int c = 0; c < 2; ++c)
                    orow[c * 16 + q] = packbf(acc[rt][c][r] * wd, acc[rt][c + 2][r] * wd);
            }
        }
}

// ---------------- layer-2 pull aggregation + log_softmax: uint4 gathers, 8 lanes/edge ----------------
// h2 row: 8 uint4 (32 u32); u32 j = feats (j, j+32).
__global__ __launch_bounds__(256) void agg2_ls_kernel(const uint32* __restrict__ h,  // N x 32
                                                      const float* __restrict__ dinv,
                                                      const int* __restrict__ srt,
                                                      const int* __restrict__ rowstart,
                                                      const int* __restrict__ rowend,
                                                      const float* __restrict__ bias,
                                                      float* __restrict__ out, int n) {
    int wid = (int)(((long)blockIdx.x * blockDim.x + threadIdx.x) >> 6);
    int lane = threadIdx.x & 63;
    if (wid >= n) return;
    const uint4* h4 = (const uint4*)h;  // row = 8 uint4
    int q = lane & 7;
    int g = lane >> 3;
    int start = rowstart[wid];
    int end = rowend[wid];
    float aL0 = 0.f, aL1 = 0.f, aL2 = 0.f, aL3 = 0.f;
    float aH0 = 0.f, aH1 = 0.f, aH2 = 0.f, aH3 = 0.f;
    if (g == 0) {  // self
        uint4 u = h4[(size_t)wid * 8 + q];
        aL0 = bf16lo(u.x); aH0 = bf16hi(u.x);
        aL1 = bf16lo(u.y); aH1 = bf16hi(u.y);
        aL2 = bf16lo(u.z); aH2 = bf16hi(u.z);
        aL3 = bf16lo(u.w); aH3 = bf16hi(u.w);
    }
    int e = start + g;
    for (; e + 24 < end; e += 32) {
        int s0 = srt[e], s1 = srt[e + 8], s2 = srt[e + 16], s3 = srt[e + 24];
        uint4 u0 = h4[(size_t)s0 * 8 + q];
        uint4 u1 = h4[(size_t)s1 * 8 + q];
        uint4 u2 = h4[(size_t)s2 * 8 + q];
        uint4 u3 = h4[(size_t)s3 * 8 + q];
        aL0 += bf16lo(u0.x); aH0 += bf16hi(u0.x); aL1 += bf16lo(u0.y); aH1 += bf16hi(u0.y);
        aL2 += bf16lo(u0.z); aH2 += bf16hi(u0.z); aL3 += bf16lo(u0.w); aH3 += bf16hi(u0.w);
        aL0 += bf16lo(u1.x); aH0 += bf16hi(u1.x); aL1 += bf16lo(u1.y); aH1 += bf16hi(u1.y);
        aL2 += bf16lo(u1.z); aH2 += bf16hi(u1.z); aL3 += bf16lo(u1.w); aH3 += bf16hi(u1.w);
        aL0 += bf16lo(u2.x); aH0 += bf16hi(u2.x); aL1 += bf16lo(u2.y); aH1 += bf16hi(u2.y);
        aL2 += bf16lo(u2.z); aH2 += bf16hi(u2.z); aL3 += bf16lo(u2.w); aH3 += bf16hi(u2.w);
        aL0 += bf16lo(u3.x); aH0 += bf16hi(u3.x); aL1 += bf16lo(u3.y); aH1 += bf16hi(u3.y);
        aL2 += bf16lo(u3.z); aH2 += bf16hi(u3.z); aL3 += bf16lo(u3.w); aH3 += bf16hi(u3.w);
    }
    for (; e < end; e += 8) {
        uint4 u = h4[(size_t)srt[e] * 8 + q];
        aL0 += bf16lo(u.x); aH0 += bf16hi(u.x); aL1 += bf16lo(u.y); aH1 += bf16hi(u.y);
        aL2 += bf16lo(u.z); aH2 += bf16hi(u.z); aL3 += bf16lo(u.w); aH3 += bf16hi(u.w);
    }
#pragma unroll
    for (int o = 8; o <= 32; o <<= 1) {
        aL0 += __shfl_xor(aL0, o, WAVE); aL1 += __shfl_xor(aL1, o, WAVE);
        aL2 += __shfl_xor(aL2, o, WAVE); aL3 += __shfl_xor(aL3, o, WAVE);
        aH0 += __shfl_xor(aH0, o, WAVE); aH1 += __shfl_xor(aH1, o, WAVE);
        aH2 += __shfl_xor(aH2, o, WAVE); aH3 += __shfl_xor(aH3, o, WAVE);
    }
    float wd = dinv[wid];
    float4 bL = *(const float4*)(bias + 4 * q);
    float4 bH = *(const float4*)(bias + 32 + 4 * q);
    float vL0 = fmaf(wd, aL0, bL.x), vL1 = fmaf(wd, aL1, bL.y);
    float vL2 = fmaf(wd, aL2, bL.z), vL3 = fmaf(wd, aL3, bL.w);
    float vH0 = fmaf(wd, aH0, bH.x), vH1 = fmaf(wd, aH1, bH.y);
    float vH2 = fmaf(wd, aH2, bH.z), vH3 = fmaf(wd, aH3, bH.w);
    float m = fmaxf(fmaxf(fmaxf(vL0, vL1), fmaxf(vL2, vL3)),
                    fmaxf(fmaxf(vH0, vH1), fmaxf(vH2, vH3)));
#pragma unroll
    for (int o = 1; o <= 4; o <<= 1) m = fmaxf(m, __shfl_xor(m, o, WAVE));
    float s = __expf(vL0 - m) + __expf(vL1 - m) + __expf(vL2 - m) + __expf(vL3 - m) +
              __expf(vH0 - m) + __expf(vH1 - m) + __expf(vH2 - m) + __expf(vH3 - m);
#pragma unroll
    for (int o = 1; o <= 4; o <<= 1) s += __shfl_xor(s, o, WAVE);
    float lg = __logf(s) + m;
    if (g == 0)
        *(float4*)&out[(size_t)wid * 64 + 4 * q] = make_float4(vL0 - lg, vL1 - lg, vL2 - lg, vL3 - lg);
    else if (g == 1)
        *(float4*)&out[(size_t)wid * 64 + 32 + 4 * q] = make_float4(vH0 - lg, vH1 - lg, vH2 - lg, vH3 - lg);
}

extern "C" void kernel_launch(void* const* d_in, const int* in_sizes, int n_in,
                              void* d_out, int out_size, void* d_ws, size_t ws_size,
                              hipStream_t stream) {
    const float* x  = (const float*)d_in[0];
    const float* W1 = (const float*)d_in[1];
    const float* b1 = (const float*)d_in[2];
    const float* W2 = (const float*)d_in[3];
    const float* b2 = (const float*)d_in[4];
    const int* edge = (const int*)d_in[5];

    const int N = in_sizes[0] / 256;
    const int E = in_sizes[5] / 2;
    const int* src = edge;
    const int* dst = edge + E;

    const int NBUCK = (N + 511) >> 9;  // <=256
    int mean = E / NBUCK;
    int CAP = mean + (int)(8.5 * __builtin_sqrt((double)mean)) + 32;
    CAP = (CAP + 63) & ~63;
    if (CAP > 36864) CAP = 36864;  // LDS flush buffer bound (144 KB)

    // ws layout (4B units): gcnt[256] | w1f[16384] | w2f[4096] | dinv[N] | rowstart[N]
    //   | rowend[N] | sorted[NBUCK*CAP] | h1a[N*32] | h1b[N*32] | h2s[N*32] | agg1bf[N*64] (pairs alias)
    int*    gcnt     = (int*)d_ws;
    uint32* w1f      = (uint32*)(gcnt + 256);
    uint32* w2f      = w1f + 16384;
    float*  dinv     = (float*)(w2f + 4096);
    int*    rowstart = (int*)(dinv + N);
    int*    rowend   = rowstart + N;
    int*    sorted   = rowend + N;
    uint32* h1a      = (uint32*)(sorted + (size_t)NBUCK * CAP);
    uint32* h1b      = h1a + (size_t)N * 32;
    uint32* h2s      = h1b + (size_t)N * 32;
    uint32* agg1bf   = h2s + (size_t)N * 32;
    uint32* pairs    = agg1bf;  // dead before agg1bf is written
    float*  outp     = (float*)d_out;

    const int TB = 256;

    // 0) weight conversion to fragment-ordered bf16 (+ zero gcnt)
    convert_w_kernel<<<80, TB, 0, stream>>>(W1, W2, w1f, w2f, gcnt);

    // 1) CSR build via two-pass bucket sort (also produces dinv)
    binsort_kernel<<<(E + BIN_EPB - 1) / BIN_EPB, BIN_TB, 0, stream>>>(src, dst, gcnt, pairs, E, CAP);
    bucket_csr_kernel<<<NBUCK, 512, (size_t)CAP * 4, stream>>>(pairs, gcnt, sorted, rowstart, rowend, dinv, N, CAP);

    // 2) h1 planes = bf16(dinv * (x @ W1))  [MFMA]
    gemm1_mfma<<<(N + 127) / 128, TB, 0, stream>>>(x, w1f, dinv, h1a, h1b, N);

    // 3) agg1bf = bf16(relu(dinv[d]*(self+sum) + b1)), two plane passes for L2 residency
    agg1_plane_kernel<<<(N * 64 + TB - 1) / TB, TB, 0, stream>>>(h1a, dinv, sorted, rowstart, rowend, b1, agg1bf, N, 0);
    agg1_plane_kernel<<<(N * 64 + TB - 1) / TB, TB, 0, stream>>>(h1b, dinv, sorted, rowstart, rowend, b1, agg1bf, N, 1);

    // 4) h2s = bf16(dinv * (agg1 @ W2))  [MFMA, bf16 A direct]
    gemm2_mfma<<<(N + 127) / 128, TB, 0, stream>>>(agg1bf, w2f, dinv, h2s, N);

    // 5) out = log_softmax(dinv[d]*(self+sum) + b2)
    agg2_ls_kernel<<<(N * 64 + TB - 1) / TB, TB, 0, stream>>>(h2s, dinv, sorted, rowstart, rowend, b2, outp, N);
}

// Round 9
// 255.206 us; speedup vs baseline: 1.0970x; 1.0970x over previous
//
#include <hip/hip_runtime.h>
#include <hip/hip_bf16.h>

#define WAVE 64
typedef unsigned int uint32;
typedef __attribute__((ext_vector_type(8))) short bf16x8;
typedef __attribute__((ext_vector_type(4))) float f32x4;
typedef __attribute__((ext_vector_type(2))) float f32x2;

// ---- bf16 helpers ----
__device__ inline float bf16lo(uint32 u) { return __uint_as_float(u << 16); }
__device__ inline float bf16hi(uint32 u) { return __uint_as_float(u & 0xffff0000u); }
__device__ inline f32x2 up2(uint32 u) {  // {lo-feat, hi-feat} as f32 pair
    return (f32x2){__uint_as_float(u << 16), __uint_as_float(u & 0xffff0000u)};
}
__device__ inline uint32 f2bf(float f) {  // round-to-nearest-even, bits in low 16
    union { float f; uint32 u; } a; a.f = f;
    uint32 u = a.u;
    u += 0x7fffu + ((u >> 16) & 1u);
    return u >> 16;
}
__device__ inline uint32 packbf(float lo, float hi) { return f2bf(lo) | (f2bf(hi) << 16); }
__device__ inline short f2bfs(float f) { return (short)f2bf(f); }
__device__ inline f32x2 shflx(f32x2 v, int o) {
    v.x = __shfl_xor(v.x, o, WAVE);
    v.y = __shfl_xor(v.y, o, WAVE);
    return v;
}

// ---------------- W1/W2 -> fragment-ordered bf16 (+ gcnt zeroing) ----------------
__global__ void convert_w_kernel(const float* __restrict__ W1, const float* __restrict__ W2,
                                 uint32* __restrict__ w1f, uint32* __restrict__ w2f,
                                 int* __restrict__ gcnt) {
    int tid = blockIdx.x * blockDim.x + threadIdx.x;  // 0..20479
    if (tid < 256) gcnt[tid] = 0;
    if (tid < 16384) {
        int w = tid & 3, l = (tid >> 2) & 63, c = (tid >> 8) & 7, kc = tid >> 11;
        int q = l & 15, g = l >> 4;
        int k0 = kc * 32 + g * 8 + 2 * w;
        int n = c * 16 + q;
        w1f[tid] = packbf(W1[k0 * 128 + n], W1[(k0 + 1) * 128 + n]);
    } else if (tid < 16384 + 4096) {
        int t = tid - 16384;
        int w = t & 3, l = (t >> 2) & 63, c = (t >> 8) & 3, kc = t >> 10;
        int q = l & 15, g = l >> 4;
        int k0 = kc * 32 + g * 8 + 2 * w;
        int n = c * 16 + q;
        w2f[t] = packbf(W2[k0 * 64 + n], W2[(k0 + 1) * 64 + n]);
    }
}

// ================= CSR build: two-pass bucket sort =================
#define BIN_TB 1024
#define BIN_EPB 4096
__global__ __launch_bounds__(BIN_TB) void binsort_kernel(const int* __restrict__ src,
                                                         const int* __restrict__ dst,
                                                         int* __restrict__ gcnt,
                                                         uint32* __restrict__ pairs,
                                                         int E, int CAP) {
    __shared__ int hist[256];
    __shared__ int scan[256];
    __shared__ int lstart[256];
    __shared__ int gbase[256];
    __shared__ int lcur[256];
    __shared__ uint32 sp[BIN_EPB];
    __shared__ unsigned char sb[BIN_EPB];
    int tid = threadIdx.x;
    int base = blockIdx.x * BIN_EPB;
    if (tid < 256) hist[tid] = 0;
    __syncthreads();
    int s[4], b[4];
    uint32 pk[4];
    bool v[4];
#pragma unroll
    for (int j = 0; j < 4; ++j) {
        int e = base + tid + j * BIN_TB;
        v[j] = e < E;
        if (v[j]) {
            s[j] = src[e];
            int d = dst[e];
            b[j] = d >> 9;
            pk[j] = (uint32)s[j] | ((uint32)(d & 511) << 17);
            atomicAdd(&hist[b[j]], 1);
        }
    }
    __syncthreads();
    if (tid < 256) scan[tid] = hist[tid];
    __syncthreads();
#pragma unroll
    for (int o = 1; o < 256; o <<= 1) {
        int t = 0;
        if (tid < 256 && tid >= o) t = scan[tid - o];
        __syncthreads();
        if (tid < 256) scan[tid] += t;
        __syncthreads();
    }
    if (tid < 256) {
        int st = scan[tid] - hist[tid];
        lstart[tid] = st;
        lcur[tid] = st;
        gbase[tid] = (hist[tid] > 0) ? (tid * CAP + atomicAdd(&gcnt[tid], hist[tid])) : 0;
    }
    __syncthreads();
#pragma unroll
    for (int j = 0; j < 4; ++j) {
        if (v[j]) {
            int p = atomicAdd(&lcur[b[j]], 1);
            sp[p] = pk[j];
            sb[p] = (unsigned char)b[j];
        }
    }
    __syncthreads();
    int total = scan[255];
    for (int i = tid; i < total; i += BIN_TB) {
        int bb = sb[i];
        pairs[gbase[bb] + (i - lstart[bb])] = sp[i];
    }
}

// Pass C: per-bucket counting sort staged in dynamic LDS, 1024 threads, coalesced flush.
__global__ __launch_bounds__(1024) void bucket_csr_kernel(const uint32* __restrict__ pairs,
                                                          const int* __restrict__ gcnt,
                                                          int* __restrict__ sorted,
                                                          int* __restrict__ rowstart,
                                                          int* __restrict__ rowend,
                                                          float* __restrict__ dinv,
                                                          int N, int CAP) {
    __shared__ int cnt[512];
    __shared__ int incl[512];
    __shared__ int cursor[512];
    extern __shared__ uint32 ssorted[];  // CAP entries
    int b = blockIdx.x;
    int tid = threadIdx.x;
    int ne = gcnt[b];
    if (ne > CAP) ne = CAP;
    const uint32* P = pairs + (size_t)b * CAP;
    if (tid < 512) cnt[tid] = 0;
    __syncthreads();
    for (int i = tid; i < ne; i += 1024) atomicAdd(&cnt[P[i] >> 17], 1);
    __syncthreads();
    int v = 0;
    if (tid < 512) { v = cnt[tid]; incl[tid] = v; }
    __syncthreads();
#pragma unroll
    for (int o = 1; o < 512; o <<= 1) {
        int t = 0;
        if (tid < 512 && tid >= o) t = incl[tid - o];
        __syncthreads();
        if (tid < 512) incl[tid] += t;
        __syncthreads();
    }
    int gbase = b * CAP;
    if (tid < 512) {
        int node = b * 512 + tid;
        if (node < N) {
            rowstart[node] = gbase + incl[tid] - v;
            rowend[node] = gbase + incl[tid];
            dinv[node] = rsqrtf(1.0f + (float)v);
        }
        cursor[tid] = incl[tid] - v;
    }
    __syncthreads();
    for (int i = tid; i < ne; i += 1024) {
        uint32 p = P[i];
        int ln = p >> 17;
        int r = atomicAdd(&cursor[ln], 1);
        ssorted[r] = p & 0x1FFFFu;
    }
    __syncthreads();
    for (int i = tid; i < ne; i += 1024) sorted[gbase + i] = (int)ssorted[i];
}

// ---------------- GEMM1 (MFMA): [N,256]fp32 @ W1F -> h1s bf16 pairs (f, f+64) ----------------
__global__ __launch_bounds__(256) void gemm1_mfma(const float* __restrict__ x,
                                                  const uint32* __restrict__ w1f,
                                                  const float* __restrict__ dinv,
                                                  uint32* __restrict__ hout,  // N x 64
                                                  int N) {
    const bf16x8* Bp = (const bf16x8*)w1f;
    int l = threadIdx.x & 63, w = threadIdx.x >> 6;
    int q = l & 15, g = l >> 4;
    int R = blockIdx.x * 128 + w * 32;
    f32x4 acc[2][8];
#pragma unroll
    for (int rt = 0; rt < 2; ++rt)
#pragma unroll
        for (int c = 0; c < 8; ++c) acc[rt][c] = (f32x4){0.f, 0.f, 0.f, 0.f};

#pragma unroll
    for (int kc = 0; kc < 8; ++kc) {
        bf16x8 b[8];
#pragma unroll
        for (int c = 0; c < 8; ++c) b[c] = Bp[(kc * 8 + c) * 64 + l];
#pragma unroll
        for (int rt = 0; rt < 2; ++rt) {
            int row = R + rt * 16 + q;
            row = row < N ? row : N - 1;
            const float* xr = x + (size_t)row * 256 + kc * 32 + g * 8;
            float4 xa = *(const float4*)xr;
            float4 xb = *(const float4*)(xr + 4);
            bf16x8 a;
            a[0] = f2bfs(xa.x); a[1] = f2bfs(xa.y); a[2] = f2bfs(xa.z); a[3] = f2bfs(xa.w);
            a[4] = f2bfs(xb.x); a[5] = f2bfs(xb.y); a[6] = f2bfs(xb.z); a[7] = f2bfs(xb.w);
#pragma unroll
            for (int c = 0; c < 8; ++c)
                acc[rt][c] = __builtin_amdgcn_mfma_f32_16x16x32_bf16(a, b[c], acc[rt][c], 0, 0, 0);
        }
    }
#pragma unroll
    for (int rt = 0; rt < 2; ++rt)
#pragma unroll
        for (int r = 0; r < 4; ++r) {
            int grow = R + rt * 16 + 4 * g + r;
            if (grow < N) {
                float wd = dinv[grow];
                uint32* orow = hout + (size_t)grow * 64;
#pragma unroll
                for (int c = 0; c < 4; ++c)
                    orow[c * 16 + q] = packbf(acc[rt][c][r] * wd, acc[rt][c + 4][r] * wd);
            }
        }
}

// ---------------- layer-1 pull aggregation: uint4 gathers, 16 lanes/edge, pk-add ----------------
// h1s row: 16 uint4 (64 u32); u32 j = feats (j, j+64).
// out: bf16 natural pairs (u32 k = feats 2k,2k+1), relu'd -> gemm2 A operand.
__global__ __launch_bounds__(256) void agg1_kernel(const uint32* __restrict__ h,
                                                   const float* __restrict__ dinv,
                                                   const int* __restrict__ srt,
                                                   const int* __restrict__ rowstart,
                                                   const int* __restrict__ rowend,
                                                   const float* __restrict__ bias,
                                                   uint32* __restrict__ out,  // N x 64
                                                   int n) {
    int wid = (int)(((long)blockIdx.x * blockDim.x + threadIdx.x) >> 6);
    int lane = threadIdx.x & 63;
    if (wid >= n) return;
    const uint4* h4 = (const uint4*)h;  // row = 16 uint4
    int q = lane & 15;
    int g = lane >> 4;
    int start = rowstart[wid];
    int end = rowend[wid];
    f32x2 a0 = {0.f, 0.f}, a1 = {0.f, 0.f}, a2 = {0.f, 0.f}, a3 = {0.f, 0.f};
    if (g == 0) {  // self (already dinv-scaled)
        uint4 u = h4[(size_t)wid * 16 + q];
        a0 = up2(u.x); a1 = up2(u.y); a2 = up2(u.z); a3 = up2(u.w);
    }
    int e = start + g;
    for (; e + 12 < end; e += 16) {  // 4 gathers in flight per 16-lane group
        int s0 = srt[e], s1 = srt[e + 4], s2 = srt[e + 8], s3 = srt[e + 12];
        uint4 u0 = h4[(size_t)s0 * 16 + q];
        uint4 u1 = h4[(size_t)s1 * 16 + q];
        uint4 u2 = h4[(size_t)s2 * 16 + q];
        uint4 u3 = h4[(size_t)s3 * 16 + q];
        a0 += up2(u0.x); a1 += up2(u0.y); a2 += up2(u0.z); a3 += up2(u0.w);
        a0 += up2(u1.x); a1 += up2(u1.y); a2 += up2(u1.z); a3 += up2(u1.w);
        a0 += up2(u2.x); a1 += up2(u2.y); a2 += up2(u2.z); a3 += up2(u2.w);
        a0 += up2(u3.x); a1 += up2(u3.y); a2 += up2(u3.z); a3 += up2(u3.w);
    }
    for (; e < end; e += 4) {
        uint4 u = h4[(size_t)srt[e] * 16 + q];
        a0 += up2(u.x); a1 += up2(u.y); a2 += up2(u.z); a3 += up2(u.w);
    }
    a0 += shflx(a0, 16); a1 += shflx(a1, 16); a2 += shflx(a2, 16); a3 += shflx(a3, 16);
    a0 += shflx(a0, 32); a1 += shflx(a1, 32); a2 += shflx(a2, 32); a3 += shflx(a3, 32);
    float wd = dinv[wid];
    if (g == 0) {  // lo plane: feats 4q..4q+3 -> out u32 2q, 2q+1
        float4 b = *(const float4*)(bias + 4 * q);
        float v0 = fmaxf(fmaf(wd, a0.x, b.x), 0.f);
        float v1 = fmaxf(fmaf(wd, a1.x, b.y), 0.f);
        float v2 = fmaxf(fmaf(wd, a2.x, b.z), 0.f);
        float v3 = fmaxf(fmaf(wd, a3.x, b.w), 0.f);
        ((uint2*)(out + (size_t)wid * 64))[q] = make_uint2(packbf(v0, v1), packbf(v2, v3));
    } else if (g == 1) {  // hi plane: feats 64+4q..64+4q+3 -> out u32 32+2q, 32+2q+1
        float4 b = *(const float4*)(bias + 64 + 4 * q);
        float v0 = fmaxf(fmaf(wd, a0.y, b.x), 0.f);
        float v1 = fmaxf(fmaf(wd, a1.y, b.y), 0.f);
        float v2 = fmaxf(fmaf(wd, a2.y, b.z), 0.f);
        float v3 = fmaxf(fmaf(wd, a3.y, b.w), 0.f);
        ((uint2*)(out + (size_t)wid * 64))[16 + q] = make_uint2(packbf(v0, v1), packbf(v2, v3));
    }
}

// ---------------- GEMM2 (MFMA): [N,128]bf16 @ W2F -> h2s bf16 pairs (f, f+32) ----------------
__global__ __launch_bounds__(256) void gemm2_mfma(const uint32* __restrict__ hin,  // N x 64 bf16-pairs
                                                  const uint32* __restrict__ w2f,
                                                  const float* __restrict__ dinv,
                                                  uint32* __restrict__ hout,  // N x 32
                                                  int N) {
    const bf16x8* Bp = (const bf16x8*)w2f;
    const short* hs = (const short*)hin;
    int l = threadIdx.x & 63, w = threadIdx.x >> 6;
    int q = l & 15, g = l >> 4;
    int R = blockIdx.x * 128 + w * 32;
    f32x4 acc[2][4];
#pragma unroll
    for (int rt = 0; rt < 2; ++rt)
#pragma unroll
        for (int c = 0; c < 4; ++c) acc[rt][c] = (f32x4){0.f, 0.f, 0.f, 0.f};

#pragma unroll
    for (int kc = 0; kc < 4; ++kc) {
        bf16x8 b[4];
#pragma unroll
        for (int c = 0; c < 4; ++c) b[c] = Bp[(kc * 4 + c) * 64 + l];
#pragma unroll
        for (int rt = 0; rt < 2; ++rt) {
            int row = R + rt * 16 + q;
            row = row < N ? row : N - 1;
            bf16x8 a = *(const bf16x8*)(hs + (size_t)row * 128 + kc * 32 + g * 8);
#pragma unroll
            for (int c = 0; c < 4; ++c)
                acc[rt][c] = __builtin_amdgcn_mfma_f32_16x16x32_bf16(a, b[c], acc[rt][c], 0, 0, 0);
        }
    }
#pragma unroll
    for (int rt = 0; rt < 2; ++rt)
#pragma unroll
        for (int r = 0; r < 4; ++r) {
            int grow = R + rt * 16 + 4 * g + r;
            if (grow < N) {
                float wd = dinv[grow];
                uint32* orow = hout + (size_t)grow * 32;
#pragma unroll
                for (int c = 0; c < 2; ++c)
                    orow[c * 16 + q] = packbf(acc[rt][c][r] * wd, acc[rt][c + 2][r] * wd);
            }
        }
}

// ---------------- layer-2 pull aggregation + log_softmax: uint4 gathers, 8 lanes/edge, pk-add ----------------
// h2 row: 8 uint4 (32 u32); u32 j = feats (j, j+32).
__global__ __launch_bounds__(256) void agg2_ls_kernel(const uint32* __restrict__ h,  // N x 32
                                                      const float* __restrict__ dinv,
                                                      const int* __restrict__ srt,
                                                      const int* __restrict__ rowstart,
                                                      const int* __restrict__ rowend,
                                                      const float* __restrict__ bias,
                                                      float* __restrict__ out, int n) {
    int wid = (int)(((long)blockIdx.x * blockDim.x + threadIdx.x) >> 6);
    int lane = threadIdx.x & 63;
    if (wid >= n) return;
    const uint4* h4 = (const uint4*)h;  // row = 8 uint4
    int q = lane & 7;
    int g = lane >> 3;
    int start = rowstart[wid];
    int end = rowend[wid];
    f32x2 a0 = {0.f, 0.f}, a1 = {0.f, 0.f}, a2 = {0.f, 0.f}, a3 = {0.f, 0.f};
    if (g == 0) {  // self
        uint4 u = h4[(size_t)wid * 8 + q];
        a0 = up2(u.x); a1 = up2(u.y); a2 = up2(u.z); a3 = up2(u.w);
    }
    int e = start + g;
    for (; e + 24 < end; e += 32) {
        int s0 = srt[e], s1 = srt[e + 8], s2 = srt[e + 16], s3 = srt[e + 24];
        uint4 u0 = h4[(size_t)s0 * 8 + q];
        uint4 u1 = h4[(size_t)s1 * 8 + q];
        uint4 u2 = h4[(size_t)s2 * 8 + q];
        uint4 u3 = h4[(size_t)s3 * 8 + q];
        a0 += up2(u0.x); a1 += up2(u0.y); a2 += up2(u0.z); a3 += up2(u0.w);
        a0 += up2(u1.x); a1 += up2(u1.y); a2 += up2(u1.z); a3 += up2(u1.w);
        a0 += up2(u2.x); a1 += up2(u2.y); a2 += up2(u2.z); a3 += up2(u2.w);
        a0 += up2(u3.x); a1 += up2(u3.y); a2 += up2(u3.z); a3 += up2(u3.w);
    }
    for (; e < end; e += 8) {
        uint4 u = h4[(size_t)srt[e] * 8 + q];
        a0 += up2(u.x); a1 += up2(u.y); a2 += up2(u.z); a3 += up2(u.w);
    }
#pragma unroll
    for (int o = 8; o <= 32; o <<= 1) {
        a0 += shflx(a0, o); a1 += shflx(a1, o); a2 += shflx(a2, o); a3 += shflx(a3, o);
    }
    float wd = dinv[wid];
    float4 bL = *(const float4*)(bias + 4 * q);
    float4 bH = *(const float4*)(bias + 32 + 4 * q);
    float vL0 = fmaf(wd, a0.x, bL.x), vL1 = fmaf(wd, a1.x, bL.y);
    float vL2 = fmaf(wd, a2.x, bL.z), vL3 = fmaf(wd, a3.x, bL.w);
    float vH0 = fmaf(wd, a0.y, bH.x), vH1 = fmaf(wd, a1.y, bH.y);
    float vH2 = fmaf(wd, a2.y, bH.z), vH3 = fmaf(wd, a3.y, bH.w);
    float m = fmaxf(fmaxf(fmaxf(vL0, vL1), fmaxf(vL2, vL3)),
                    fmaxf(fmaxf(vH0, vH1), fmaxf(vH2, vH3)));
#pragma unroll
    for (int o = 1; o <= 4; o <<= 1) m = fmaxf(m, __shfl_xor(m, o, WAVE));
    float s = __expf(vL0 - m) + __expf(vL1 - m) + __expf(vL2 - m) + __expf(vL3 - m) +
              __expf(vH0 - m) + __expf(vH1 - m) + __expf(vH2 - m) + __expf(vH3 - m);
#pragma unroll
    for (int o = 1; o <= 4; o <<= 1) s += __shfl_xor(s, o, WAVE);
    float lg = __logf(s) + m;
    if (g == 0)
        *(float4*)&out[(size_t)wid * 64 + 4 * q] = make_float4(vL0 - lg, vL1 - lg, vL2 - lg, vL3 - lg);
    else if (g == 1)
        *(float4*)&out[(size_t)wid * 64 + 32 + 4 * q] = make_float4(vH0 - lg, vH1 - lg, vH2 - lg, vH3 - lg);
}

extern "C" void kernel_launch(void* const* d_in, const int* in_sizes, int n_in,
                              void* d_out, int out_size, void* d_ws, size_t ws_size,
                              hipStream_t stream) {
    const float* x  = (const float*)d_in[0];
    const float* W1 = (const float*)d_in[1];
    const float* b1 = (const float*)d_in[2];
    const float* W2 = (const float*)d_in[3];
    const float* b2 = (const float*)d_in[4];
    const int* edge = (const int*)d_in[5];

    const int N = in_sizes[0] / 256;
    const int E = in_sizes[5] / 2;
    const int* src = edge;
    const int* dst = edge + E;

    const int NBUCK = (N + 511) >> 9;  // <=256
    int mean = E / NBUCK;
    int CAP = mean + (int)(8.5 * __builtin_sqrt((double)mean)) + 32;
    CAP = (CAP + 63) & ~63;
    if (CAP > 36864) CAP = 36864;  // LDS flush buffer bound (144 KB)

    // ws layout (4B units): gcnt[256] | w1f[16384] | w2f[4096] | dinv[N] | rowstart[N]
    //   | rowend[N] | sorted[NBUCK*CAP] | h1s[N*64] | h2s[N*32] | agg1bf[N*64] (pairs alias)
    int*    gcnt     = (int*)d_ws;
    uint32* w1f      = (uint32*)(gcnt + 256);
    uint32* w2f      = w1f + 16384;
    float*  dinv     = (float*)(w2f + 4096);
    int*    rowstart = (int*)(dinv + N);
    int*    rowend   = rowstart + N;
    int*    sorted   = rowend + N;
    uint32* h1s      = (uint32*)(sorted + (size_t)NBUCK * CAP);
    uint32* h2s      = h1s + (size_t)N * 64;
    uint32* agg1bf   = h2s + (size_t)N * 32;
    uint32* pairs    = agg1bf;  // dead before agg1bf is written
    float*  outp     = (float*)d_out;

    const int TB = 256;

    // 0) weight conversion to fragment-ordered bf16 (+ zero gcnt)
    convert_w_kernel<<<80, TB, 0, stream>>>(W1, W2, w1f, w2f, gcnt);

    // 1) CSR build via two-pass bucket sort (also produces dinv)
    binsort_kernel<<<(E + BIN_EPB - 1) / BIN_EPB, BIN_TB, 0, stream>>>(src, dst, gcnt, pairs, E, CAP);
    bucket_csr_kernel<<<NBUCK, 1024, (size_t)CAP * 4, stream>>>(pairs, gcnt, sorted, rowstart, rowend, dinv, N, CAP);

    // 2) h1s = bf16(dinv * (x @ W1))  [MFMA]
    gemm1_mfma<<<(N + 127) / 128, TB, 0, stream>>>(x, w1f, dinv, h1s, N);

    // 3) agg1bf = bf16(relu(dinv[d]*(self+sum) + b1)), single pass, natural order
    agg1_kernel<<<(N * 64 + TB - 1) / TB, TB, 0, stream>>>(h1s, dinv, sorted, rowstart, rowend, b1, agg1bf, N);

    // 4) h2s = bf16(dinv * (agg1 @ W2))  [MFMA, bf16 A direct]
    gemm2_mfma<<<(N + 127) / 128, TB, 0, stream>>>(agg1bf, w2f, dinv, h2s, N);

    // 5) out = log_softmax(dinv[d]*(self+sum) + b2)
    agg2_ls_kernel<<<(N * 64 + TB - 1) / TB, TB, 0, stream>>>(h2s, dinv, sorted, rowstart, rowend, b2, outp, N);
}

// Round 10
// 238.666 us; speedup vs baseline: 1.1730x; 1.0693x over previous
//
#include <hip/hip_runtime.h>
#include <hip/hip_bf16.h>

#define WAVE 64
typedef unsigned int uint32;
typedef __attribute__((ext_vector_type(8))) short bf16x8;
typedef __attribute__((ext_vector_type(4))) float f32x4;
typedef __attribute__((ext_vector_type(2))) float f32x2;

// ---- bf16 helpers ----
__device__ inline f32x2 up2(uint32 u) {  // {lo-feat, hi-feat} as f32 pair
    return (f32x2){__uint_as_float(u << 16), __uint_as_float(u & 0xffff0000u)};
}
__device__ inline uint32 f2bf(float f) {  // round-to-nearest-even, bits in low 16
    union { float f; uint32 u; } a; a.f = f;
    uint32 u = a.u;
    u += 0x7fffu + ((u >> 16) & 1u);
    return u >> 16;
}
__device__ inline uint32 packbf(float lo, float hi) { return f2bf(lo) | (f2bf(hi) << 16); }
__device__ inline short f2bfs(float f) { return (short)f2bf(f); }
__device__ inline f32x2 shflx(f32x2 v, int o) {
    v.x = __shfl_xor(v.x, o, WAVE);
    v.y = __shfl_xor(v.y, o, WAVE);
    return v;
}
// ---- fp8 e4m3 helpers (HW cvt, OCP on gfx950) ----
template <bool HI>
__device__ inline f32x2 up8(uint32 u) {  // bytes (0,1) or (2,3) -> {lo, hi} f32
    return __builtin_amdgcn_cvt_pk_f32_fp8((int)u, HI);
}
__device__ inline unsigned short pack8(float lo, float hi) {
    return (unsigned short)__builtin_amdgcn_cvt_pk_fp8_f32(lo, hi, 0, false);
}

// ---------------- W1/W2 -> fragment-ordered bf16 (+ gcnt zeroing) ----------------
__global__ void convert_w_kernel(const float* __restrict__ W1, const float* __restrict__ W2,
                                 uint32* __restrict__ w1f, uint32* __restrict__ w2f,
                                 int* __restrict__ gcnt) {
    int tid = blockIdx.x * blockDim.x + threadIdx.x;  // 0..20479
    if (tid < 256) gcnt[tid] = 0;
    if (tid < 16384) {
        int w = tid & 3, l = (tid >> 2) & 63, c = (tid >> 8) & 7, kc = tid >> 11;
        int q = l & 15, g = l >> 4;
        int k0 = kc * 32 + g * 8 + 2 * w;
        int n = c * 16 + q;
        w1f[tid] = packbf(W1[k0 * 128 + n], W1[(k0 + 1) * 128 + n]);
    } else if (tid < 16384 + 4096) {
        int t = tid - 16384;
        int w = t & 3, l = (t >> 2) & 63, c = (t >> 8) & 3, kc = t >> 10;
        int q = l & 15, g = l >> 4;
        int k0 = kc * 32 + g * 8 + 2 * w;
        int n = c * 16 + q;
        w2f[t] = packbf(W2[k0 * 64 + n], W2[(k0 + 1) * 64 + n]);
    }
}

// ================= CSR build: two-pass bucket sort =================
#define BIN_TB 1024
#define BIN_EPB 4096
__global__ __launch_bounds__(BIN_TB) void binsort_kernel(const int* __restrict__ src,
                                                         const int* __restrict__ dst,
                                                         int* __restrict__ gcnt,
                                                         uint32* __restrict__ pairs,
                                                         int E, int CAP) {
    __shared__ int hist[256];
    __shared__ int scan[256];
    __shared__ int lstart[256];
    __shared__ int gbase[256];
    __shared__ int lcur[256];
    __shared__ uint32 sp[BIN_EPB];
    __shared__ unsigned char sb[BIN_EPB];
    int tid = threadIdx.x;
    int base = blockIdx.x * BIN_EPB;
    if (tid < 256) hist[tid] = 0;
    __syncthreads();
    int s[4], b[4];
    uint32 pk[4];
    bool v[4];
#pragma unroll
    for (int j = 0; j < 4; ++j) {
        int e = base + tid + j * BIN_TB;
        v[j] = e < E;
        if (v[j]) {
            s[j] = src[e];
            int d = dst[e];
            b[j] = d >> 9;
            pk[j] = (uint32)s[j] | ((uint32)(d & 511) << 17);
            atomicAdd(&hist[b[j]], 1);
        }
    }
    __syncthreads();
    if (tid < 256) scan[tid] = hist[tid];
    __syncthreads();
#pragma unroll
    for (int o = 1; o < 256; o <<= 1) {
        int t = 0;
        if (tid < 256 && tid >= o) t = scan[tid - o];
        __syncthreads();
        if (tid < 256) scan[tid] += t;
        __syncthreads();
    }
    if (tid < 256) {
        int st = scan[tid] - hist[tid];
        lstart[tid] = st;
        lcur[tid] = st;
        gbase[tid] = (hist[tid] > 0) ? (tid * CAP + atomicAdd(&gcnt[tid], hist[tid])) : 0;
    }
    __syncthreads();
#pragma unroll
    for (int j = 0; j < 4; ++j) {
        if (v[j]) {
            int p = atomicAdd(&lcur[b[j]], 1);
            sp[p] = pk[j];
            sb[p] = (unsigned char)b[j];
        }
    }
    __syncthreads();
    int total = scan[255];
    for (int i = tid; i < total; i += BIN_TB) {
        int bb = sb[i];
        pairs[gbase[bb] + (i - lstart[bb])] = sp[i];
    }
}

// Pass C: per-bucket counting sort staged in dynamic LDS, 1024 threads, coalesced flush.
__global__ __launch_bounds__(1024) void bucket_csr_kernel(const uint32* __restrict__ pairs,
                                                          const int* __restrict__ gcnt,
                                                          int* __restrict__ sorted,
                                                          int* __restrict__ rowstart,
                                                          int* __restrict__ rowend,
                                                          float* __restrict__ dinv,
                                                          int N, int CAP) {
    __shared__ int cnt[512];
    __shared__ int incl[512];
    __shared__ int cursor[512];
    extern __shared__ uint32 ssorted[];  // CAP entries
    int b = blockIdx.x;
    int tid = threadIdx.x;
    int ne = gcnt[b];
    if (ne > CAP) ne = CAP;
    const uint32* P = pairs + (size_t)b * CAP;
    if (tid < 512) cnt[tid] = 0;
    __syncthreads();
    for (int i = tid; i < ne; i += 1024) atomicAdd(&cnt[P[i] >> 17], 1);
    __syncthreads();
    int v = 0;
    if (tid < 512) { v = cnt[tid]; incl[tid] = v; }
    __syncthreads();
#pragma unroll
    for (int o = 1; o < 512; o <<= 1) {
        int t = 0;
        if (tid < 512 && tid >= o) t = incl[tid - o];
        __syncthreads();
        if (tid < 512) incl[tid] += t;
        __syncthreads();
    }
    int gbase = b * CAP;
    if (tid < 512) {
        int node = b * 512 + tid;
        if (node < N) {
            rowstart[node] = gbase + incl[tid] - v;
            rowend[node] = gbase + incl[tid];
            dinv[node] = rsqrtf(1.0f + (float)v);
        }
        cursor[tid] = incl[tid] - v;
    }
    __syncthreads();
    for (int i = tid; i < ne; i += 1024) {
        uint32 p = P[i];
        int ln = p >> 17;
        int r = atomicAdd(&cursor[ln], 1);
        ssorted[r] = p & 0x1FFFFu;
    }
    __syncthreads();
    for (int i = tid; i < ne; i += 1024) sorted[gbase + i] = (int)ssorted[i];
}

// ---------------- GEMM1 (MFMA): [N,256]fp32 @ W1F -> h1f fp8, u16 slot j = (f_j, f_j+64) ----------------
__global__ __launch_bounds__(256) void gemm1_mfma(const float* __restrict__ x,
                                                  const uint32* __restrict__ w1f,
                                                  const float* __restrict__ dinv,
                                                  unsigned short* __restrict__ h1f,  // N x 64 u16
                                                  int N) {
    const bf16x8* Bp = (const bf16x8*)w1f;
    int l = threadIdx.x & 63, w = threadIdx.x >> 6;
    int q = l & 15, g = l >> 4;
    int R = blockIdx.x * 128 + w * 32;
    f32x4 acc[2][8];
#pragma unroll
    for (int rt = 0; rt < 2; ++rt)
#pragma unroll
        for (int c = 0; c < 8; ++c) acc[rt][c] = (f32x4){0.f, 0.f, 0.f, 0.f};

#pragma unroll
    for (int kc = 0; kc < 8; ++kc) {
        bf16x8 b[8];
#pragma unroll
        for (int c = 0; c < 8; ++c) b[c] = Bp[(kc * 8 + c) * 64 + l];
#pragma unroll
        for (int rt = 0; rt < 2; ++rt) {
            int row = R + rt * 16 + q;
            row = row < N ? row : N - 1;
            const float* xr = x + (size_t)row * 256 + kc * 32 + g * 8;
            float4 xa = *(const float4*)xr;
            float4 xb = *(const float4*)(xr + 4);
            bf16x8 a;
            a[0] = f2bfs(xa.x); a[1] = f2bfs(xa.y); a[2] = f2bfs(xa.z); a[3] = f2bfs(xa.w);
            a[4] = f2bfs(xb.x); a[5] = f2bfs(xb.y); a[6] = f2bfs(xb.z); a[7] = f2bfs(xb.w);
#pragma unroll
            for (int c = 0; c < 8; ++c)
                acc[rt][c] = __builtin_amdgcn_mfma_f32_16x16x32_bf16(a, b[c], acc[rt][c], 0, 0, 0);
        }
    }
#pragma unroll
    for (int rt = 0; rt < 2; ++rt)
#pragma unroll
        for (int r = 0; r < 4; ++r) {
            int grow = R + rt * 16 + 4 * g + r;
            if (grow < N) {
                float wd = dinv[grow];
                unsigned short* orow = h1f + (size_t)grow * 64;
#pragma unroll
                for (int c = 0; c < 4; ++c)
                    orow[c * 16 + q] = pack8(acc[rt][c][r] * wd, acc[rt][c + 4][r] * wd);
            }
        }
}

// ---------------- layer-1 pull aggregation: fp8 rows (128 B), uint4 gathers, 8 lanes/edge ----------------
// h1f row: 8 uint4 = 64 u16 slots; slot j = fp8 (feat j, feat j+64).
// out: bf16 natural pairs (u32 k = feats 2k,2k+1), relu'd -> gemm2 A operand.
__global__ __launch_bounds__(256) void agg1_kernel(const unsigned short* __restrict__ h1f,
                                                   const float* __restrict__ dinv,
                                                   const int* __restrict__ srt,
                                                   const int* __restrict__ rowstart,
                                                   const int* __restrict__ rowend,
                                                   const float* __restrict__ bias,
                                                   uint32* __restrict__ out,  // N x 64
                                                   int n) {
    int wid = (int)(((long)blockIdx.x * blockDim.x + threadIdx.x) >> 6);
    int lane = threadIdx.x & 63;
    if (wid >= n) return;
    const uint4* h4 = (const uint4*)h1f;  // row = 8 uint4
    int q = lane & 7;
    int g = lane >> 3;
    int start = rowstart[wid];
    int end = rowend[wid];
    f32x2 a0 = {0.f, 0.f}, a1 = {0.f, 0.f}, a2 = {0.f, 0.f}, a3 = {0.f, 0.f};
    f32x2 a4 = {0.f, 0.f}, a5 = {0.f, 0.f}, a6 = {0.f, 0.f}, a7 = {0.f, 0.f};
    if (g == 0) {  // self (already dinv-scaled)
        uint4 u = h4[(size_t)wid * 8 + q];
        a0 = up8<false>(u.x); a1 = up8<true>(u.x);
        a2 = up8<false>(u.y); a3 = up8<true>(u.y);
        a4 = up8<false>(u.z); a5 = up8<true>(u.z);
        a6 = up8<false>(u.w); a7 = up8<true>(u.w);
    }
    int e = start + g;
    for (; e + 24 < end; e += 32) {  // 4 gathers in flight per 8-lane group
        int s0 = srt[e], s1 = srt[e + 8], s2 = srt[e + 16], s3 = srt[e + 24];
        uint4 u0 = h4[(size_t)s0 * 8 + q];
        uint4 u1 = h4[(size_t)s1 * 8 + q];
        uint4 u2 = h4[(size_t)s2 * 8 + q];
        uint4 u3 = h4[(size_t)s3 * 8 + q];
        a0 += up8<false>(u0.x); a1 += up8<true>(u0.x); a2 += up8<false>(u0.y); a3 += up8<true>(u0.y);
        a4 += up8<false>(u0.z); a5 += up8<true>(u0.z); a6 += up8<false>(u0.w); a7 += up8<true>(u0.w);
        a0 += up8<false>(u1.x); a1 += up8<true>(u1.x); a2 += up8<false>(u1.y); a3 += up8<true>(u1.y);
        a4 += up8<false>(u1.z); a5 += up8<true>(u1.z); a6 += up8<false>(u1.w); a7 += up8<true>(u1.w);
        a0 += up8<false>(u2.x); a1 += up8<true>(u2.x); a2 += up8<false>(u2.y); a3 += up8<true>(u2.y);
        a4 += up8<false>(u2.z); a5 += up8<true>(u2.z); a6 += up8<false>(u2.w); a7 += up8<true>(u2.w);
        a0 += up8<false>(u3.x); a1 += up8<true>(u3.x); a2 += up8<false>(u3.y); a3 += up8<true>(u3.y);
        a4 += up8<false>(u3.z); a5 += up8<true>(u3.z); a6 += up8<false>(u3.w); a7 += up8<true>(u3.w);
    }
    for (; e < end; e += 8) {
        uint4 u = h4[(size_t)srt[e] * 8 + q];
        a0 += up8<false>(u.x); a1 += up8<true>(u.x); a2 += up8<false>(u.y); a3 += up8<true>(u.y);
        a4 += up8<false>(u.z); a5 += up8<true>(u.z); a6 += up8<false>(u.w); a7 += up8<true>(u.w);
    }
#pragma unroll
    for (int o = 8; o <= 32; o <<= 1) {
        a0 += shflx(a0, o); a1 += shflx(a1, o); a2 += shflx(a2, o); a3 += shflx(a3, o);
        a4 += shflx(a4, o); a5 += shflx(a5, o); a6 += shflx(a6, o); a7 += shflx(a7, o);
    }
    float wd = dinv[wid];
    if (g < 2) {  // g==0: lo plane (feats 8q..8q+7); g==1: hi plane (feats 64+8q..)
        int fb = (g == 0) ? 8 * q : 64 + 8 * q;
        float4 ba = *(const float4*)(bias + fb);
        float4 bb = *(const float4*)(bias + fb + 4);
        float v0, v1, v2, v3, v4, v5, v6, v7;
        if (g == 0) {
            v0 = a0.x; v1 = a1.x; v2 = a2.x; v3 = a3.x;
            v4 = a4.x; v5 = a5.x; v6 = a6.x; v7 = a7.x;
        } else {
            v0 = a0.y; v1 = a1.y; v2 = a2.y; v3 = a3.y;
            v4 = a4.y; v5 = a5.y; v6 = a6.y; v7 = a7.y;
        }
        v0 = fmaxf(fmaf(wd, v0, ba.x), 0.f); v1 = fmaxf(fmaf(wd, v1, ba.y), 0.f);
        v2 = fmaxf(fmaf(wd, v2, ba.z), 0.f); v3 = fmaxf(fmaf(wd, v3, ba.w), 0.f);
        v4 = fmaxf(fmaf(wd, v4, bb.x), 0.f); v5 = fmaxf(fmaf(wd, v5, bb.y), 0.f);
        v6 = fmaxf(fmaf(wd, v6, bb.z), 0.f); v7 = fmaxf(fmaf(wd, v7, bb.w), 0.f);
        uint4 o4;
        o4.x = packbf(v0, v1); o4.y = packbf(v2, v3);
        o4.z = packbf(v4, v5); o4.w = packbf(v6, v7);
        ((uint4*)(out + (size_t)wid * 64))[g * 8 + q] = o4;
    }
}

// ---------------- GEMM2 (MFMA): [N,128]bf16 @ W2F -> h2s bf16 pairs (f, f+32) ----------------
__global__ __launch_bounds__(256) void gemm2_mfma(const uint32* __restrict__ hin,  // N x 64 bf16-pairs
                                                  const uint32* __restrict__ w2f,
                                                  const float* __restrict__ dinv,
                                                  uint32* __restrict__ hout,  // N x 32
                                                  int N) {
    const bf16x8* Bp = (const bf16x8*)w2f;
    const short* hs = (const short*)hin;
    int l = threadIdx.x & 63, w = threadIdx.x >> 6;
    int q = l & 15, g = l >> 4;
    int R = blockIdx.x * 128 + w * 32;
    f32x4 acc[2][4];
#pragma unroll
    for (int rt = 0; rt < 2; ++rt)
#pragma unroll
        for (int c = 0; c < 4; ++c) acc[rt][c] = (f32x4){0.f, 0.f, 0.f, 0.f};

#pragma unroll
    for (int kc = 0; kc < 4; ++kc) {
        bf16x8 b[4];
#pragma unroll
        for (int c = 0; c < 4; ++c) b[c] = Bp[(kc * 4 + c) * 64 + l];
#pragma unroll
        for (int rt = 0; rt < 2; ++rt) {
            int row = R + rt * 16 + q;
            row = row < N ? row : N - 1;
            bf16x8 a = *(const bf16x8*)(hs + (size_t)row * 128 + kc * 32 + g * 8);
#pragma unroll
            for (int c = 0; c < 4; ++c)
                acc[rt][c] = __builtin_amdgcn_mfma_f32_16x16x32_bf16(a, b[c], acc[rt][c], 0, 0, 0);
        }
    }
#pragma unroll
    for (int rt = 0; rt < 2; ++rt)
#pragma unroll
        for (int r = 0; r < 4; ++r) {
            int grow = R + rt * 16 + 4 * g + r;
            if (grow < N) {
                float wd = dinv[grow];
                uint32* orow = hout + (size_t)grow * 32;
#pragma unroll
                for (int c = 0; c < 2; ++c)
                    orow[c * 16 + q] = packbf(acc[rt][c][r] * wd, acc[rt][c + 2][r] * wd);
            }
        }
}

// ---------------- layer-2 pull aggregation + log_softmax: uint4 gathers, 8 lanes/edge, pk-add ----------------
// h2 row: 8 uint4 (32 u32); u32 j = feats (j, j+32).
__global__ __launch_bounds__(256) void agg2_ls_kernel(const uint32* __restrict__ h,  // N x 32
                                                      const float* __restrict__ dinv,
                                                      const int* __restrict__ srt,
                                                      const int* __restrict__ rowstart,
                                                      const int* __restrict__ rowend,
                                                      const float* __restrict__ bias,
                                                      float* __restrict__ out, int n) {
    int wid = (int)(((long)blockIdx.x * blockDim.x + threadIdx.x) >> 6);
    int lane = threadIdx.x & 63;
    if (wid >= n) return;
    const uint4* h4 = (const uint4*)h;  // row = 8 uint4
    int q = lane & 7;
    int g = lane >> 3;
    int start = rowstart[wid];
    int end = rowend[wid];
    f32x2 a0 = {0.f, 0.f}, a1 = {0.f, 0.f}, a2 = {0.f, 0.f}, a3 = {0.f, 0.f};
    if (g == 0) {  // self
        uint4 u = h4[(size_t)wid * 8 + q];
        a0 = up2(u.x); a1 = up2(u.y); a2 = up2(u.z); a3 = up2(u.w);
    }
    int e = start + g;
    for (; e + 24 < end; e += 32) {
        int s0 = srt[e], s1 = srt[e + 8], s2 = srt[e + 16], s3 = srt[e + 24];
        uint4 u0 = h4[(size_t)s0 * 8 + q];
        uint4 u1 = h4[(size_t)s1 * 8 + q];
        uint4 u2 = h4[(size_t)s2 * 8 + q];
        uint4 u3 = h4[(size_t)s3 * 8 + q];
        a0 += up2(u0.x); a1 += up2(u0.y); a2 += up2(u0.z); a3 += up2(u0.w);
        a0 += up2(u1.x); a1 += up2(u1.y); a2 += up2(u1.z); a3 += up2(u1.w);
        a0 += up2(u2.x); a1 += up2(u2.y); a2 += up2(u2.z); a3 += up2(u2.w);
        a0 += up2(u3.x); a1 += up2(u3.y); a2 += up2(u3.z); a3 += up2(u3.w);
    }
    for (; e < end; e += 8) {
        uint4 u = h4[(size_t)srt[e] * 8 + q];
        a0 += up2(u.x); a1 += up2(u.y); a2 += up2(u.z); a3 += up2(u.w);
    }
#pragma unroll
    for (int o = 8; o <= 32; o <<= 1) {
        a0 += shflx(a0, o); a1 += shflx(a1, o); a2 += shflx(a2, o); a3 += shflx(a3, o);
    }
    float wd = dinv[wid];
    float4 bL = *(const float4*)(bias + 4 * q);
    float4 bH = *(const float4*)(bias + 32 + 4 * q);
    float vL0 = fmaf(wd, a0.x, bL.x), vL1 = fmaf(wd, a1.x, bL.y);
    float vL2 = fmaf(wd, a2.x, bL.z), vL3 = fmaf(wd, a3.x, bL.w);
    float vH0 = fmaf(wd, a0.y, bH.x), vH1 = fmaf(wd, a1.y, bH.y);
    float vH2 = fmaf(wd, a2.y, bH.z), vH3 = fmaf(wd, a3.y, bH.w);
    float m = fmaxf(fmaxf(fmaxf(vL0, vL1), fmaxf(vL2, vL3)),
                    fmaxf(fmaxf(vH0, vH1), fmaxf(vH2, vH3)));
#pragma unroll
    for (int o = 1; o <= 4; o <<= 1) m = fmaxf(m, __shfl_xor(m, o, WAVE));
    float s = __expf(vL0 - m) + __expf(vL1 - m) + __expf(vL2 - m) + __expf(vL3 - m) +
              __expf(vH0 - m) + __expf(vH1 - m) + __expf(vH2 - m) + __expf(vH3 - m);
#pragma unroll
    for (int o = 1; o <= 4; o <<= 1) s += __shfl_xor(s, o, WAVE);
    float lg = __logf(s) + m;
    if (g == 0)
        *(float4*)&out[(size_t)wid * 64 + 4 * q] = make_float4(vL0 - lg, vL1 - lg, vL2 - lg, vL3 - lg);
    else if (g == 1)
        *(float4*)&out[(size_t)wid * 64 + 32 + 4 * q] = make_float4(vH0 - lg, vH1 - lg, vH2 - lg, vH3 - lg);
}

extern "C" void kernel_launch(void* const* d_in, const int* in_sizes, int n_in,
                              void* d_out, int out_size, void* d_ws, size_t ws_size,
                              hipStream_t stream) {
    const float* x  = (const float*)d_in[0];
    const float* W1 = (const float*)d_in[1];
    const float* b1 = (const float*)d_in[2];
    const float* W2 = (const float*)d_in[3];
    const float* b2 = (const float*)d_in[4];
    const int* edge = (const int*)d_in[5];

    const int N = in_sizes[0] / 256;
    const int E = in_sizes[5] / 2;
    const int* src = edge;
    const int* dst = edge + E;

    const int NBUCK = (N + 511) >> 9;  // <=256
    int mean = E / NBUCK;
    int CAP = mean + (int)(8.5 * __builtin_sqrt((double)mean)) + 32;
    CAP = (CAP + 63) & ~63;
    if (CAP > 36864) CAP = 36864;  // LDS flush buffer bound (144 KB)

    // ws layout (4B units): gcnt[256] | w1f[16384] | w2f[4096] | dinv[N] | rowstart[N]
    //   | rowend[N] | sorted[NBUCK*CAP] | h1f[N*32] | h2s[N*32] | agg1bf[N*64] (pairs alias)
    int*    gcnt     = (int*)d_ws;
    uint32* w1f      = (uint32*)(gcnt + 256);
    uint32* w2f      = w1f + 16384;
    float*  dinv     = (float*)(w2f + 4096);
    int*    rowstart = (int*)(dinv + N);
    int*    rowend   = rowstart + N;
    int*    sorted   = rowend + N;
    unsigned short* h1f = (unsigned short*)(sorted + (size_t)NBUCK * CAP);  // N x 64 u16
    uint32* h2s      = (uint32*)(h1f + (size_t)N * 64);
    uint32* agg1bf   = h2s + (size_t)N * 32;
    uint32* pairs    = agg1bf;  // dead before agg1bf is written
    float*  outp     = (float*)d_out;

    const int TB = 256;

    // 0) weight conversion to fragment-ordered bf16 (+ zero gcnt)
    convert_w_kernel<<<80, TB, 0, stream>>>(W1, W2, w1f, w2f, gcnt);

    // 1) CSR build via two-pass bucket sort (also produces dinv)
    binsort_kernel<<<(E + BIN_EPB - 1) / BIN_EPB, BIN_TB, 0, stream>>>(src, dst, gcnt, pairs, E, CAP);
    bucket_csr_kernel<<<NBUCK, 1024, (size_t)CAP * 4, stream>>>(pairs, gcnt, sorted, rowstart, rowend, dinv, N, CAP);

    // 2) h1f = fp8(dinv * (x @ W1))  [MFMA]
    gemm1_mfma<<<(N + 127) / 128, TB, 0, stream>>>(x, w1f, dinv, h1f, N);

    // 3) agg1bf = bf16(relu(dinv[d]*(self+sum) + b1)), fp8 gather, natural order
    agg1_kernel<<<(N * 64 + TB - 1) / TB, TB, 0, stream>>>(h1f, dinv, sorted, rowstart, rowend, b1, agg1bf, N);

    // 4) h2s = bf16(dinv * (agg1 @ W2))  [MFMA, bf16 A direct]
    gemm2_mfma<<<(N + 127) / 128, TB, 0, stream>>>(agg1bf, w2f, dinv, h2s, N);

    // 5) out = log_softmax(dinv[d]*(self+sum) + b2)
    agg2_ls_kernel<<<(N * 64 + TB - 1) / TB, TB, 0, stream>>>(h2s, dinv, sorted, rowstart, rowend, b2, outp, N);
}

// Round 11
// 233.369 us; speedup vs baseline: 1.1996x; 1.0227x over previous
//
#include <hip/hip_runtime.h>
#include <hip/hip_bf16.h>

#define WAVE 64
typedef unsigned int uint32;
typedef __attribute__((ext_vector_type(8))) short bf16x8;
typedef __attribute__((ext_vector_type(4))) float f32x4;
typedef __attribute__((ext_vector_type(2))) float f32x2;

// ---- bf16 helpers ----
__device__ inline uint32 f2bf(float f) {  // round-to-nearest-even, bits in low 16
    union { float f; uint32 u; } a; a.f = f;
    uint32 u = a.u;
    u += 0x7fffu + ((u >> 16) & 1u);
    return u >> 16;
}
__device__ inline uint32 packbf(float lo, float hi) { return f2bf(lo) | (f2bf(hi) << 16); }
__device__ inline short f2bfs(float f) { return (short)f2bf(f); }
__device__ inline f32x2 shflx(f32x2 v, int o) {
    v.x = __shfl_xor(v.x, o, WAVE);
    v.y = __shfl_xor(v.y, o, WAVE);
    return v;
}
// ---- fp8 e4m3 helpers (HW cvt, OCP on gfx950) ----
template <bool HI>
__device__ inline f32x2 up8(uint32 u) {  // bytes (0,1) or (2,3) -> {lo, hi} f32
    return __builtin_amdgcn_cvt_pk_f32_fp8((int)u, HI);
}
__device__ inline unsigned short pack8(float lo, float hi) {
    return (unsigned short)__builtin_amdgcn_cvt_pk_fp8_f32(lo, hi, 0, false);
}

// ---------------- W1/W2 -> fragment-ordered bf16 (+ gcnt zeroing) ----------------
__global__ void convert_w_kernel(const float* __restrict__ W1, const float* __restrict__ W2,
                                 uint32* __restrict__ w1f, uint32* __restrict__ w2f,
                                 int* __restrict__ gcnt) {
    int tid = blockIdx.x * blockDim.x + threadIdx.x;  // 0..20479
    if (tid < 256) gcnt[tid] = 0;
    if (tid < 16384) {
        int w = tid & 3, l = (tid >> 2) & 63, c = (tid >> 8) & 7, kc = tid >> 11;
        int q = l & 15, g = l >> 4;
        int k0 = kc * 32 + g * 8 + 2 * w;
        int n = c * 16 + q;
        w1f[tid] = packbf(W1[k0 * 128 + n], W1[(k0 + 1) * 128 + n]);
    } else if (tid < 16384 + 4096) {
        int t = tid - 16384;
        int w = t & 3, l = (t >> 2) & 63, c = (t >> 8) & 3, kc = t >> 10;
        int q = l & 15, g = l >> 4;
        int k0 = kc * 32 + g * 8 + 2 * w;
        int n = c * 16 + q;
        w2f[t] = packbf(W2[k0 * 64 + n], W2[(k0 + 1) * 64 + n]);
    }
}

// ================= CSR build: two-pass bucket sort =================
#define BIN_TB 1024
#define BIN_EPB 4096
__global__ __launch_bounds__(BIN_TB) void binsort_kernel(const int* __restrict__ src,
                                                         const int* __restrict__ dst,
                                                         int* __restrict__ gcnt,
                                                         uint32* __restrict__ pairs,
                                                         int E, int CAP) {
    __shared__ int hist[256];
    __shared__ int scan[256];
    __shared__ int lstart[256];
    __shared__ int gbase[256];
    __shared__ int lcur[256];
    __shared__ uint32 sp[BIN_EPB];
    __shared__ unsigned char sb[BIN_EPB];
    int tid = threadIdx.x;
    int base = blockIdx.x * BIN_EPB;
    if (tid < 256) hist[tid] = 0;
    __syncthreads();
    int s[4], b[4];
    uint32 pk[4];
    bool v[4];
#pragma unroll
    for (int j = 0; j < 4; ++j) {
        int e = base + tid + j * BIN_TB;
        v[j] = e < E;
        if (v[j]) {
            s[j] = src[e];
            int d = dst[e];
            b[j] = d >> 9;
            pk[j] = (uint32)s[j] | ((uint32)(d & 511) << 17);
            atomicAdd(&hist[b[j]], 1);
        }
    }
    __syncthreads();
    if (tid < 256) scan[tid] = hist[tid];
    __syncthreads();
#pragma unroll
    for (int o = 1; o < 256; o <<= 1) {
        int t = 0;
        if (tid < 256 && tid >= o) t = scan[tid - o];
        __syncthreads();
        if (tid < 256) scan[tid] += t;
        __syncthreads();
    }
    if (tid < 256) {
        int st = scan[tid] - hist[tid];
        lstart[tid] = st;
        lcur[tid] = st;
        gbase[tid] = (hist[tid] > 0) ? (tid * CAP + atomicAdd(&gcnt[tid], hist[tid])) : 0;
    }
    __syncthreads();
#pragma unroll
    for (int j = 0; j < 4; ++j) {
        if (v[j]) {
            int p = atomicAdd(&lcur[b[j]], 1);
            sp[p] = pk[j];
            sb[p] = (unsigned char)b[j];
        }
    }
    __syncthreads();
    int total = scan[255];
    for (int i = tid; i < total; i += BIN_TB) {
        int bb = sb[i];
        pairs[gbase[bb] + (i - lstart[bb])] = sp[i];
    }
}

// Pass C: per-bucket counting sort staged in dynamic LDS, 1024 threads, coalesced flush.
__global__ __launch_bounds__(1024) void bucket_csr_kernel(const uint32* __restrict__ pairs,
                                                          const int* __restrict__ gcnt,
                                                          int* __restrict__ sorted,
                                                          int* __restrict__ rowstart,
                                                          int* __restrict__ rowend,
                                                          float* __restrict__ dinv,
                                                          int N, int CAP) {
    __shared__ int cnt[512];
    __shared__ int incl[512];
    __shared__ int cursor[512];
    extern __shared__ uint32 ssorted[];  // CAP entries
    int b = blockIdx.x;
    int tid = threadIdx.x;
    int ne = gcnt[b];
    if (ne > CAP) ne = CAP;
    const uint32* P = pairs + (size_t)b * CAP;
    if (tid < 512) cnt[tid] = 0;
    __syncthreads();
    for (int i = tid; i < ne; i += 1024) atomicAdd(&cnt[P[i] >> 17], 1);
    __syncthreads();
    int v = 0;
    if (tid < 512) { v = cnt[tid]; incl[tid] = v; }
    __syncthreads();
#pragma unroll
    for (int o = 1; o < 512; o <<= 1) {
        int t = 0;
        if (tid < 512 && tid >= o) t = incl[tid - o];
        __syncthreads();
        if (tid < 512) incl[tid] += t;
        __syncthreads();
    }
    int gbase = b * CAP;
    if (tid < 512) {
        int node = b * 512 + tid;
        if (node < N) {
            rowstart[node] = gbase + incl[tid] - v;
            rowend[node] = gbase + incl[tid];
            dinv[node] = rsqrtf(1.0f + (float)v);
        }
        cursor[tid] = incl[tid] - v;
    }
    __syncthreads();
    for (int i = tid; i < ne; i += 1024) {
        uint32 p = P[i];
        int ln = p >> 17;
        int r = atomicAdd(&cursor[ln], 1);
        ssorted[r] = p & 0x1FFFFu;
    }
    __syncthreads();
    for (int i = tid; i < ne; i += 1024) sorted[gbase + i] = (int)ssorted[i];
}

// ---------------- GEMM1 (MFMA): [N,256]fp32 @ W1F -> h1f fp8, u16 slot j = (f_j, f_j+64) ----------------
__global__ __launch_bounds__(256) void gemm1_mfma(const float* __restrict__ x,
                                                  const uint32* __restrict__ w1f,
                                                  const float* __restrict__ dinv,
                                                  unsigned short* __restrict__ h1f,  // N x 64 u16
                                                  int N) {
    const bf16x8* Bp = (const bf16x8*)w1f;
    int l = threadIdx.x & 63, w = threadIdx.x >> 6;
    int q = l & 15, g = l >> 4;
    int R = blockIdx.x * 128 + w * 32;
    f32x4 acc[2][8];
#pragma unroll
    for (int rt = 0; rt < 2; ++rt)
#pragma unroll
        for (int c = 0; c < 8; ++c) acc[rt][c] = (f32x4){0.f, 0.f, 0.f, 0.f};

#pragma unroll
    for (int kc = 0; kc < 8; ++kc) {
        bf16x8 b[8];
#pragma unroll
        for (int c = 0; c < 8; ++c) b[c] = Bp[(kc * 8 + c) * 64 + l];
#pragma unroll
        for (int rt = 0; rt < 2; ++rt) {
            int row = R + rt * 16 + q;
            row = row < N ? row : N - 1;
            const float* xr = x + (size_t)row * 256 + kc * 32 + g * 8;
            float4 xa = *(const float4*)xr;
            float4 xb = *(const float4*)(xr + 4);
            bf16x8 a;
            a[0] = f2bfs(xa.x); a[1] = f2bfs(xa.y); a[2] = f2bfs(xa.z); a[3] = f2bfs(xa.w);
            a[4] = f2bfs(xb.x); a[5] = f2bfs(xb.y); a[6] = f2bfs(xb.z); a[7] = f2bfs(xb.w);
#pragma unroll
            for (int c = 0; c < 8; ++c)
                acc[rt][c] = __builtin_amdgcn_mfma_f32_16x16x32_bf16(a, b[c], acc[rt][c], 0, 0, 0);
        }
    }
#pragma unroll
    for (int rt = 0; rt < 2; ++rt)
#pragma unroll
        for (int r = 0; r < 4; ++r) {
            int grow = R + rt * 16 + 4 * g + r;
            if (grow < N) {
                float wd = dinv[grow];
                unsigned short* orow = h1f + (size_t)grow * 64;
#pragma unroll
                for (int c = 0; c < 4; ++c)
                    orow[c * 16 + q] = pack8(acc[rt][c][r] * wd, acc[rt][c + 4][r] * wd);
            }
        }
}

// ---------------- layer-1 pull aggregation: fp8 rows (128 B), uint4 gathers, 8 lanes/edge ----------------
__global__ __launch_bounds__(256) void agg1_kernel(const unsigned short* __restrict__ h1f,
                                                   const float* __restrict__ dinv,
                                                   const int* __restrict__ srt,
                                                   const int* __restrict__ rowstart,
                                                   const int* __restrict__ rowend,
                                                   const float* __restrict__ bias,
                                                   uint32* __restrict__ out,  // N x 64
                                                   int n) {
    int wid = (int)(((long)blockIdx.x * blockDim.x + threadIdx.x) >> 6);
    int lane = threadIdx.x & 63;
    if (wid >= n) return;
    const uint4* h4 = (const uint4*)h1f;  // row = 8 uint4
    int q = lane & 7;
    int g = lane >> 3;
    int start = rowstart[wid];
    int end = rowend[wid];
    f32x2 a0 = {0.f, 0.f}, a1 = {0.f, 0.f}, a2 = {0.f, 0.f}, a3 = {0.f, 0.f};
    f32x2 a4 = {0.f, 0.f}, a5 = {0.f, 0.f}, a6 = {0.f, 0.f}, a7 = {0.f, 0.f};
    if (g == 0) {  // self (already dinv-scaled)
        uint4 u = h4[(size_t)wid * 8 + q];
        a0 = up8<false>(u.x); a1 = up8<true>(u.x);
        a2 = up8<false>(u.y); a3 = up8<true>(u.y);
        a4 = up8<false>(u.z); a5 = up8<true>(u.z);
        a6 = up8<false>(u.w); a7 = up8<true>(u.w);
    }
    int e = start + g;
    for (; e + 24 < end; e += 32) {  // 4 gathers in flight per 8-lane group
        int s0 = srt[e], s1 = srt[e + 8], s2 = srt[e + 16], s3 = srt[e + 24];
        uint4 u0 = h4[(size_t)s0 * 8 + q];
        uint4 u1 = h4[(size_t)s1 * 8 + q];
        uint4 u2 = h4[(size_t)s2 * 8 + q];
        uint4 u3 = h4[(size_t)s3 * 8 + q];
        a0 += up8<false>(u0.x); a1 += up8<true>(u0.x); a2 += up8<false>(u0.y); a3 += up8<true>(u0.y);
        a4 += up8<false>(u0.z); a5 += up8<true>(u0.z); a6 += up8<false>(u0.w); a7 += up8<true>(u0.w);
        a0 += up8<false>(u1.x); a1 += up8<true>(u1.x); a2 += up8<false>(u1.y); a3 += up8<true>(u1.y);
        a4 += up8<false>(u1.z); a5 += up8<true>(u1.z); a6 += up8<false>(u1.w); a7 += up8<true>(u1.w);
        a0 += up8<false>(u2.x); a1 += up8<true>(u2.x); a2 += up8<false>(u2.y); a3 += up8<true>(u2.y);
        a4 += up8<false>(u2.z); a5 += up8<true>(u2.z); a6 += up8<false>(u2.w); a7 += up8<true>(u2.w);
        a0 += up8<false>(u3.x); a1 += up8<true>(u3.x); a2 += up8<false>(u3.y); a3 += up8<true>(u3.y);
        a4 += up8<false>(u3.z); a5 += up8<true>(u3.z); a6 += up8<false>(u3.w); a7 += up8<true>(u3.w);
    }
    for (; e < end; e += 8) {
        uint4 u = h4[(size_t)srt[e] * 8 + q];
        a0 += up8<false>(u.x); a1 += up8<true>(u.x); a2 += up8<false>(u.y); a3 += up8<true>(u.y);
        a4 += up8<false>(u.z); a5 += up8<true>(u.z); a6 += up8<false>(u.w); a7 += up8<true>(u.w);
    }
#pragma unroll
    for (int o = 8; o <= 32; o <<= 1) {
        a0 += shflx(a0, o); a1 += shflx(a1, o); a2 += shflx(a2, o); a3 += shflx(a3, o);
        a4 += shflx(a4, o); a5 += shflx(a5, o); a6 += shflx(a6, o); a7 += shflx(a7, o);
    }
    float wd = dinv[wid];
    if (g < 2) {  // g==0: lo plane (feats 8q..8q+7); g==1: hi plane (feats 64+8q..)
        int fb = (g == 0) ? 8 * q : 64 + 8 * q;
        float4 ba = *(const float4*)(bias + fb);
        float4 bb = *(const float4*)(bias + fb + 4);
        float v0, v1, v2, v3, v4, v5, v6, v7;
        if (g == 0) {
            v0 = a0.x; v1 = a1.x; v2 = a2.x; v3 = a3.x;
            v4 = a4.x; v5 = a5.x; v6 = a6.x; v7 = a7.x;
        } else {
            v0 = a0.y; v1 = a1.y; v2 = a2.y; v3 = a3.y;
            v4 = a4.y; v5 = a5.y; v6 = a6.y; v7 = a7.y;
        }
        v0 = fmaxf(fmaf(wd, v0, ba.x), 0.f); v1 = fmaxf(fmaf(wd, v1, ba.y), 0.f);
        v2 = fmaxf(fmaf(wd, v2, ba.z), 0.f); v3 = fmaxf(fmaf(wd, v3, ba.w), 0.f);
        v4 = fmaxf(fmaf(wd, v4, bb.x), 0.f); v5 = fmaxf(fmaf(wd, v5, bb.y), 0.f);
        v6 = fmaxf(fmaf(wd, v6, bb.z), 0.f); v7 = fmaxf(fmaf(wd, v7, bb.w), 0.f);
        uint4 o4;
        o4.x = packbf(v0, v1); o4.y = packbf(v2, v3);
        o4.z = packbf(v4, v5); o4.w = packbf(v6, v7);
        ((uint4*)(out + (size_t)wid * 64))[g * 8 + q] = o4;
    }
}

// ---------------- GEMM2 (MFMA): [N,128]bf16 @ W2F -> h2f fp8, u16 slot j = (f_j, f_j+32) ----------------
__global__ __launch_bounds__(256) void gemm2_mfma(const uint32* __restrict__ hin,  // N x 64 bf16-pairs
                                                  const uint32* __restrict__ w2f,
                                                  const float* __restrict__ dinv,
                                                  unsigned short* __restrict__ h2f,  // N x 32 u16
                                                  int N) {
    const bf16x8* Bp = (const bf16x8*)w2f;
    const short* hs = (const short*)hin;
    int l = threadIdx.x & 63, w = threadIdx.x >> 6;
    int q = l & 15, g = l >> 4;
    int R = blockIdx.x * 128 + w * 32;
    f32x4 acc[2][4];
#pragma unroll
    for (int rt = 0; rt < 2; ++rt)
#pragma unroll
        for (int c = 0; c < 4; ++c) acc[rt][c] = (f32x4){0.f, 0.f, 0.f, 0.f};

#pragma unroll
    for (int kc = 0; kc < 4; ++kc) {
        bf16x8 b[4];
#pragma unroll
        for (int c = 0; c < 4; ++c) b[c] = Bp[(kc * 4 + c) * 64 + l];
#pragma unroll
        for (int rt = 0; rt < 2; ++rt) {
            int row = R + rt * 16 + q;
            row = row < N ? row : N - 1;
            bf16x8 a = *(const bf16x8*)(hs + (size_t)row * 128 + kc * 32 + g * 8);
#pragma unroll
            for (int c = 0; c < 4; ++c)
                acc[rt][c] = __builtin_amdgcn_mfma_f32_16x16x32_bf16(a, b[c], acc[rt][c], 0, 0, 0);
        }
    }
#pragma unroll
    for (int rt = 0; rt < 2; ++rt)
#pragma unroll
        for (int r = 0; r < 4; ++r) {
            int grow = R + rt * 16 + 4 * g + r;
            if (grow < N) {
                float wd = dinv[grow];
                unsigned short* orow = h2f + (size_t)grow * 32;
#pragma unroll
                for (int c = 0; c < 2; ++c)
                    orow[c * 16 + q] = pack8(acc[rt][c][r] * wd, acc[rt][c + 2][r] * wd);
            }
        }
}

// ---------------- layer-2 pull aggregation + log_softmax: fp8 rows (64 B), uint2 gathers ----------------
// h2f row: 8 uint2 = 32 u16 slots; slot j = fp8 (feat j, feat j+32).
__global__ __launch_bounds__(256) void agg2_ls_kernel(const unsigned short* __restrict__ h2f,
                                                      const float* __restrict__ dinv,
                                                      const int* __restrict__ srt,
                                                      const int* __restrict__ rowstart,
                                                      const int* __restrict__ rowend,
                                                      const float* __restrict__ bias,
                                                      float* __restrict__ out, int n) {
    int wid = (int)(((long)blockIdx.x * blockDim.x + threadIdx.x) >> 6);
    int lane = threadIdx.x & 63;
    if (wid >= n) return;
    const uint2* h2 = (const uint2*)h2f;  // row = 8 uint2
    int q = lane & 7;
    int g = lane >> 3;
    int start = rowstart[wid];
    int end = rowend[wid];
    f32x2 a0 = {0.f, 0.f}, a1 = {0.f, 0.f}, a2 = {0.f, 0.f}, a3 = {0.f, 0.f};
    if (g == 0) {  // self
        uint2 u = h2[(size_t)wid * 8 + q];
        a0 = up8<false>(u.x); a1 = up8<true>(u.x);
        a2 = up8<false>(u.y); a3 = up8<true>(u.y);
    }
    int e = start + g;
    for (; e + 24 < end; e += 32) {  // 4 gathers in flight per 8-lane group
        int s0 = srt[e], s1 = srt[e + 8], s2 = srt[e + 16], s3 = srt[e + 24];
        uint2 u0 = h2[(size_t)s0 * 8 + q];
        uint2 u1 = h2[(size_t)s1 * 8 + q];
        uint2 u2 = h2[(size_t)s2 * 8 + q];
        uint2 u3 = h2[(size_t)s3 * 8 + q];
        a0 += up8<false>(u0.x); a1 += up8<true>(u0.x); a2 += up8<false>(u0.y); a3 += up8<true>(u0.y);
        a0 += up8<false>(u1.x); a1 += up8<true>(u1.x); a2 += up8<false>(u1.y); a3 += up8<true>(u1.y);
        a0 += up8<false>(u2.x); a1 += up8<true>(u2.x); a2 += up8<false>(u2.y); a3 += up8<true>(u2.y);
        a0 += up8<false>(u3.x); a1 += up8<true>(u3.x); a2 += up8<false>(u3.y); a3 += up8<true>(u3.y);
    }
    for (; e < end; e += 8) {
        uint2 u = h2[(size_t)srt[e] * 8 + q];
        a0 += up8<false>(u.x); a1 += up8<true>(u.x);
        a2 += up8<false>(u.y); a3 += up8<true>(u.y);
    }
#pragma unroll
    for (int o = 8; o <= 32; o <<= 1) {
        a0 += shflx(a0, o); a1 += shflx(a1, o); a2 += shflx(a2, o); a3 += shflx(a3, o);
    }
    // lane q: lo = feats 4q..4q+3 (a0.x,a1.x,a2.x,a3.x), hi = feats 32+4q.. (a0.y..)
    float wd = dinv[wid];
    float4 bL = *(const float4*)(bias + 4 * q);
    float4 bH = *(const float4*)(bias + 32 + 4 * q);
    float vL0 = fmaf(wd, a0.x, bL.x), vL1 = fmaf(wd, a1.x, bL.y);
    float vL2 = fmaf(wd, a2.x, bL.z), vL3 = fmaf(wd, a3.x, bL.w);
    float vH0 = fmaf(wd, a0.y, bH.x), vH1 = fmaf(wd, a1.y, bH.y);
    float vH2 = fmaf(wd, a2.y, bH.z), vH3 = fmaf(wd, a3.y, bH.w);
    float m = fmaxf(fmaxf(fmaxf(vL0, vL1), fmaxf(vL2, vL3)),
                    fmaxf(fmaxf(vH0, vH1), fmaxf(vH2, vH3)));
#pragma unroll
    for (int o = 1; o <= 4; o <<= 1) m = fmaxf(m, __shfl_xor(m, o, WAVE));
    float s = __expf(vL0 - m) + __expf(vL1 - m) + __expf(vL2 - m) + __expf(vL3 - m) +
              __expf(vH0 - m) + __expf(vH1 - m) + __expf(vH2 - m) + __expf(vH3 - m);
#pragma unroll
    for (int o = 1; o <= 4; o <<= 1) s += __shfl_xor(s, o, WAVE);
    float lg = __logf(s) + m;
    if (g == 0)
        *(float4*)&out[(size_t)wid * 64 + 4 * q] = make_float4(vL0 - lg, vL1 - lg, vL2 - lg, vL3 - lg);
    else if (g == 1)
        *(float4*)&out[(size_t)wid * 64 + 32 + 4 * q] = make_float4(vH0 - lg, vH1 - lg, vH2 - lg, vH3 - lg);
}

extern "C" void kernel_launch(void* const* d_in, const int* in_sizes, int n_in,
                              void* d_out, int out_size, void* d_ws, size_t ws_size,
                              hipStream_t stream) {
    const float* x  = (const float*)d_in[0];
    const float* W1 = (const float*)d_in[1];
    const float* b1 = (const float*)d_in[2];
    const float* W2 = (const float*)d_in[3];
    const float* b2 = (const float*)d_in[4];
    const int* edge = (const int*)d_in[5];

    const int N = in_sizes[0] / 256;
    const int E = in_sizes[5] / 2;
    const int* src = edge;
    const int* dst = edge + E;

    const int NBUCK = (N + 511) >> 9;  // <=256
    int mean = E / NBUCK;
    int CAP = mean + (int)(8.5 * __builtin_sqrt((double)mean)) + 32;
    CAP = (CAP + 63) & ~63;
    if (CAP > 36864) CAP = 36864;  // LDS flush buffer bound (144 KB)

    // ws layout (4B units): gcnt[256] | w1f[16384] | w2f[4096] | dinv[N] | rowstart[N]
    //   | rowend[N] | sorted[NBUCK*CAP] | h1f[N*32] | h2f[N*16] | agg1bf[N*64] (pairs alias)
    int*    gcnt     = (int*)d_ws;
    uint32* w1f      = (uint32*)(gcnt + 256);
    uint32* w2f      = w1f + 16384;
    float*  dinv     = (float*)(w2f + 4096);
    int*    rowstart = (int*)(dinv + N);
    int*    rowend   = rowstart + N;
    int*    sorted   = rowend + N;
    unsigned short* h1f = (unsigned short*)(sorted + (size_t)NBUCK * CAP);  // N x 64 u16
    unsigned short* h2f = h1f + (size_t)N * 64;                             // N x 32 u16
    uint32* agg1bf   = (uint32*)(h2f + (size_t)N * 32);
    uint32* pairs    = agg1bf;  // dead before agg1bf is written
    float*  outp     = (float*)d_out;

    const int TB = 256;

    // 0) weight conversion to fragment-ordered bf16 (+ zero gcnt)
    convert_w_kernel<<<80, TB, 0, stream>>>(W1, W2, w1f, w2f, gcnt);

    // 1) CSR build via two-pass bucket sort (also produces dinv)
    binsort_kernel<<<(E + BIN_EPB - 1) / BIN_EPB, BIN_TB, 0, stream>>>(src, dst, gcnt, pairs, E, CAP);
    bucket_csr_kernel<<<NBUCK, 1024, (size_t)CAP * 4, stream>>>(pairs, gcnt, sorted, rowstart, rowend, dinv, N, CAP);

    // 2) h1f = fp8(dinv * (x @ W1))  [MFMA]
    gemm1_mfma<<<(N + 127) / 128, TB, 0, stream>>>(x, w1f, dinv, h1f, N);

    // 3) agg1bf = bf16(relu(dinv[d]*(self+sum) + b1)), fp8 gather, natural order
    agg1_kernel<<<(N * 64 + TB - 1) / TB, TB, 0, stream>>>(h1f, dinv, sorted, rowstart, rowend, b1, agg1bf, N);

    // 4) h2f = fp8(dinv * (agg1 @ W2))  [MFMA, bf16 A direct]
    gemm2_mfma<<<(N + 127) / 128, TB, 0, stream>>>(agg1bf, w2f, dinv, h2f, N);

    // 5) out = log_softmax(dinv[d]*(self+sum) + b2), fp8 gather
    agg2_ls_kernel<<<(N * 64 + TB - 1) / TB, TB, 0, stream>>>(h2f, dinv, sorted, rowstart, rowend, b2, outp, N);
}

// Round 12
// 219.757 us; speedup vs baseline: 1.2739x; 1.0619x over previous
//
#include <hip/hip_runtime.h>
#include <hip/hip_bf16.h>

#define WAVE 64
typedef unsigned int uint32;
typedef __attribute__((ext_vector_type(8))) short bf16x8;
typedef __attribute__((ext_vector_type(4))) float f32x4;
typedef __attribute__((ext_vector_type(2))) float f32x2;

// ---- bf16 helpers ----
__device__ inline uint32 f2bf(float f) {  // round-to-nearest-even, bits in low 16
    union { float f; uint32 u; } a; a.f = f;
    uint32 u = a.u;
    u += 0x7fffu + ((u >> 16) & 1u);
    return u >> 16;
}
__device__ inline uint32 packbf(float lo, float hi) { return f2bf(lo) | (f2bf(hi) << 16); }
__device__ inline short f2bfs(float f) { return (short)f2bf(f); }
__device__ inline f32x2 shflx(f32x2 v, int o) {
    v.x = __shfl_xor(v.x, o, WAVE);
    v.y = __shfl_xor(v.y, o, WAVE);
    return v;
}
// ---- fp8 e4m3 helpers (HW cvt, OCP on gfx950) ----
template <bool HI>
__device__ inline f32x2 up8(uint32 u) {  // bytes (0,1) or (2,3) -> {lo, hi} f32
    return __builtin_amdgcn_cvt_pk_f32_fp8((int)u, HI);
}
__device__ inline unsigned short pack8(float lo, float hi) {
    return (unsigned short)__builtin_amdgcn_cvt_pk_fp8_f32(lo, hi, 0, false);
}

// ---------------- W1/W2 -> fragment-ordered bf16 (+ gcnt zeroing) ----------------
__global__ void convert_w_kernel(const float* __restrict__ W1, const float* __restrict__ W2,
                                 uint32* __restrict__ w1f, uint32* __restrict__ w2f,
                                 int* __restrict__ gcnt) {
    int tid = blockIdx.x * blockDim.x + threadIdx.x;  // 0..20479
    if (tid < 256) gcnt[tid] = 0;
    if (tid < 16384) {
        int w = tid & 3, l = (tid >> 2) & 63, c = (tid >> 8) & 7, kc = tid >> 11;
        int q = l & 15, g = l >> 4;
        int k0 = kc * 32 + g * 8 + 2 * w;
        int n = c * 16 + q;
        w1f[tid] = packbf(W1[k0 * 128 + n], W1[(k0 + 1) * 128 + n]);
    } else if (tid < 16384 + 4096) {
        int t = tid - 16384;
        int w = t & 3, l = (t >> 2) & 63, c = (t >> 8) & 3, kc = t >> 10;
        int q = l & 15, g = l >> 4;
        int k0 = kc * 32 + g * 8 + 2 * w;
        int n = c * 16 + q;
        w2f[t] = packbf(W2[k0 * 64 + n], W2[(k0 + 1) * 64 + n]);
    }
}

// ================= CSR build: two-pass bucket sort =================
#define BIN_TB 1024
#define BIN_EPB 4096
__global__ __launch_bounds__(BIN_TB) void binsort_kernel(const int* __restrict__ src,
                                                         const int* __restrict__ dst,
                                                         int* __restrict__ gcnt,
                                                         uint32* __restrict__ pairs,
                                                         int E, int CAP) {
    __shared__ int hist[256];
    __shared__ int scan[256];
    __shared__ int lstart[256];
    __shared__ int gbase[256];
    __shared__ int lcur[256];
    __shared__ uint32 sp[BIN_EPB];
    __shared__ unsigned char sb[BIN_EPB];
    int tid = threadIdx.x;
    int base = blockIdx.x * BIN_EPB;
    if (tid < 256) hist[tid] = 0;
    __syncthreads();
    int s[4], b[4];
    uint32 pk[4];
    bool v[4];
#pragma unroll
    for (int j = 0; j < 4; ++j) {
        int e = base + tid + j * BIN_TB;
        v[j] = e < E;
        if (v[j]) {
            s[j] = src[e];
            int d = dst[e];
            b[j] = d >> 9;
            pk[j] = (uint32)s[j] | ((uint32)(d & 511) << 17);
            atomicAdd(&hist[b[j]], 1);
        }
    }
    __syncthreads();
    if (tid < 256) scan[tid] = hist[tid];
    __syncthreads();
#pragma unroll
    for (int o = 1; o < 256; o <<= 1) {
        int t = 0;
        if (tid < 256 && tid >= o) t = scan[tid - o];
        __syncthreads();
        if (tid < 256) scan[tid] += t;
        __syncthreads();
    }
    if (tid < 256) {
        int st = scan[tid] - hist[tid];
        lstart[tid] = st;
        lcur[tid] = st;
        gbase[tid] = (hist[tid] > 0) ? (tid * CAP + atomicAdd(&gcnt[tid], hist[tid])) : 0;
    }
    __syncthreads();
#pragma unroll
    for (int j = 0; j < 4; ++j) {
        if (v[j]) {
            int p = atomicAdd(&lcur[b[j]], 1);
            sp[p] = pk[j];
            sb[p] = (unsigned char)b[j];
        }
    }
    __syncthreads();
    int total = scan[255];
    for (int i = tid; i < total; i += BIN_TB) {
        int bb = sb[i];
        pairs[gbase[bb] + (i - lstart[bb])] = sp[i];
    }
}

// Pass C: per-bucket counting sort staged in dynamic LDS, 1024 threads, coalesced flush.
__global__ __launch_bounds__(1024) void bucket_csr_kernel(const uint32* __restrict__ pairs,
                                                          const int* __restrict__ gcnt,
                                                          int* __restrict__ sorted,
                                                          int* __restrict__ rowstart,
                                                          int* __restrict__ rowend,
                                                          float* __restrict__ dinv,
                                                          int N, int CAP) {
    __shared__ int cnt[512];
    __shared__ int incl[512];
    __shared__ int cursor[512];
    extern __shared__ uint32 ssorted[];  // CAP entries
    int b = blockIdx.x;
    int tid = threadIdx.x;
    int ne = gcnt[b];
    if (ne > CAP) ne = CAP;
    const uint32* P = pairs + (size_t)b * CAP;
    if (tid < 512) cnt[tid] = 0;
    __syncthreads();
    for (int i = tid; i < ne; i += 1024) atomicAdd(&cnt[P[i] >> 17], 1);
    __syncthreads();
    int v = 0;
    if (tid < 512) { v = cnt[tid]; incl[tid] = v; }
    __syncthreads();
#pragma unroll
    for (int o = 1; o < 512; o <<= 1) {
        int t = 0;
        if (tid < 512 && tid >= o) t = incl[tid - o];
        __syncthreads();
        if (tid < 512) incl[tid] += t;
        __syncthreads();
    }
    int gbase = b * CAP;
    if (tid < 512) {
        int node = b * 512 + tid;
        if (node < N) {
            rowstart[node] = gbase + incl[tid] - v;
            rowend[node] = gbase + incl[tid];
            dinv[node] = rsqrtf(1.0f + (float)v);
        }
        cursor[tid] = incl[tid] - v;
    }
    __syncthreads();
    for (int i = tid; i < ne; i += 1024) {
        uint32 p = P[i];
        int ln = p >> 17;
        int r = atomicAdd(&cursor[ln], 1);
        ssorted[r] = p & 0x1FFFFu;
    }
    __syncthreads();
    for (int i = tid; i < ne; i += 1024) sorted[gbase + i] = (int)ssorted[i];
}

// ---------------- GEMM1 (MFMA): [N,256]fp32 @ W1F -> h1f fp8, u16 slot j = (f_j, f_j+64) ----------------
__global__ __launch_bounds__(256) void gemm1_mfma(const float* __restrict__ x,
                                                  const uint32* __restrict__ w1f,
                                                  const float* __restrict__ dinv,
                                                  unsigned short* __restrict__ h1f,  // N x 64 u16
                                                  int N) {
    const bf16x8* Bp = (const bf16x8*)w1f;
    int l = threadIdx.x & 63, w = threadIdx.x >> 6;
    int q = l & 15, g = l >> 4;
    int R = blockIdx.x * 128 + w * 32;
    f32x4 acc[2][8];
#pragma unroll
    for (int rt = 0; rt < 2; ++rt)
#pragma unroll
        for (int c = 0; c < 8; ++c) acc[rt][c] = (f32x4){0.f, 0.f, 0.f, 0.f};

#pragma unroll
    for (int kc = 0; kc < 8; ++kc) {
        bf16x8 b[8];
#pragma unroll
        for (int c = 0; c < 8; ++c) b[c] = Bp[(kc * 8 + c) * 64 + l];
#pragma unroll
        for (int rt = 0; rt < 2; ++rt) {
            int row = R + rt * 16 + q;
            row = row < N ? row : N - 1;
            const float* xr = x + (size_t)row * 256 + kc * 32 + g * 8;
            float4 xa = *(const float4*)xr;
            float4 xb = *(const float4*)(xr + 4);
            bf16x8 a;
            a[0] = f2bfs(xa.x); a[1] = f2bfs(xa.y); a[2] = f2bfs(xa.z); a[3] = f2bfs(xa.w);
            a[4] = f2bfs(xb.x); a[5] = f2bfs(xb.y); a[6] = f2bfs(xb.z); a[7] = f2bfs(xb.w);
#pragma unroll
            for (int c = 0; c < 8; ++c)
                acc[rt][c] = __builtin_amdgcn_mfma_f32_16x16x32_bf16(a, b[c], acc[rt][c], 0, 0, 0);
        }
    }
#pragma unroll
    for (int rt = 0; rt < 2; ++rt)
#pragma unroll
        for (int r = 0; r < 4; ++r) {
            int grow = R + rt * 16 + 4 * g + r;
            if (grow < N) {
                float wd = dinv[grow];
                unsigned short* orow = h1f + (size_t)grow * 64;
#pragma unroll
                for (int c = 0; c < 4; ++c)
                    orow[c * 16 + q] = pack8(acc[rt][c][r] * wd, acc[rt][c + 4][r] * wd);
            }
        }
}

// ---------------- layer-1 pull aggregation: lane-owns-slot, no cross-lane reduce ----------------
// h1f row = 32 u32 (128 B). Half-wave per edge: lane q in [0,32) loads u32 slot q.
// u32 slot q = feats (2q, 2q+64, 2q+1, 2q+65). Halves take alternate edges; one
// shfl_xor(32) combine at the end. Out: bf16 natural pairs (u32 k = feats 2k,2k+1).
__global__ __launch_bounds__(256) void agg1_kernel(const uint32* __restrict__ h1,  // N x 32 u32
                                                   const float* __restrict__ dinv,
                                                   const int* __restrict__ srt,
                                                   const int* __restrict__ rowstart,
                                                   const int* __restrict__ rowend,
                                                   const float* __restrict__ bias,
                                                   uint32* __restrict__ out,  // N x 64
                                                   int n) {
    int wid = (int)(((long)blockIdx.x * blockDim.x + threadIdx.x) >> 6);
    int lane = threadIdx.x & 63;
    if (wid >= n) return;
    int q = lane & 31;
    int half = lane >> 5;
    int start = rowstart[wid];
    int end = rowend[wid];
    f32x2 aL = {0.f, 0.f}, aH = {0.f, 0.f};  // aL=(f2q, f2q+64), aH=(f2q+1, f2q+65)
    if (half == 0) {  // self (already dinv-scaled)
        uint32 u = h1[(size_t)wid * 32 + q];
        aL = up8<false>(u); aH = up8<true>(u);
    }
    int e = start + half;
    for (; e + 6 < end; e += 8) {  // 4 edges in flight per half-wave
        int s0 = srt[e], s1 = srt[e + 2], s2 = srt[e + 4], s3 = srt[e + 6];
        uint32 u0 = h1[(size_t)s0 * 32 + q];
        uint32 u1 = h1[(size_t)s1 * 32 + q];
        uint32 u2 = h1[(size_t)s2 * 32 + q];
        uint32 u3 = h1[(size_t)s3 * 32 + q];
        aL += up8<false>(u0); aH += up8<true>(u0);
        aL += up8<false>(u1); aH += up8<true>(u1);
        aL += up8<false>(u2); aH += up8<true>(u2);
        aL += up8<false>(u3); aH += up8<true>(u3);
    }
    for (; e < end; e += 2) {
        uint32 u = h1[(size_t)srt[e] * 32 + q];
        aL += up8<false>(u); aH += up8<true>(u);
    }
    aL += shflx(aL, 32);
    aH += shflx(aH, 32);
    if (half == 0) {
        float wd = dinv[wid];
        float2 b0 = ((const float2*)bias)[q];        // b[2q], b[2q+1]
        float2 b1 = ((const float2*)bias)[q + 32];   // b[2q+64], b[2q+65]
        float v0 = fmaxf(fmaf(wd, aL.x, b0.x), 0.f); // f2q
        float v1 = fmaxf(fmaf(wd, aH.x, b0.y), 0.f); // f2q+1
        float v2 = fmaxf(fmaf(wd, aL.y, b1.x), 0.f); // f2q+64
        float v3 = fmaxf(fmaf(wd, aH.y, b1.y), 0.f); // f2q+65
        uint32* orow = out + (size_t)wid * 64;
        orow[q] = packbf(v0, v1);
        orow[32 + q] = packbf(v2, v3);
    }
}

// ---------------- GEMM2 (MFMA): [N,128]bf16 @ W2F -> h2f fp8, u16 slot j = (f_j, f_j+32) ----------------
__global__ __launch_bounds__(256) void gemm2_mfma(const uint32* __restrict__ hin,  // N x 64 bf16-pairs
                                                  const uint32* __restrict__ w2f,
                                                  const float* __restrict__ dinv,
                                                  unsigned short* __restrict__ h2f,  // N x 32 u16
                                                  int N) {
    const bf16x8* Bp = (const bf16x8*)w2f;
    const short* hs = (const short*)hin;
    int l = threadIdx.x & 63, w = threadIdx.x >> 6;
    int q = l & 15, g = l >> 4;
    int R = blockIdx.x * 128 + w * 32;
    f32x4 acc[2][4];
#pragma unroll
    for (int rt = 0; rt < 2; ++rt)
#pragma unroll
        for (int c = 0; c < 4; ++c) acc[rt][c] = (f32x4){0.f, 0.f, 0.f, 0.f};

#pragma unroll
    for (int kc = 0; kc < 4; ++kc) {
        bf16x8 b[4];
#pragma unroll
        for (int c = 0; c < 4; ++c) b[c] = Bp[(kc * 4 + c) * 64 + l];
#pragma unroll
        for (int rt = 0; rt < 2; ++rt) {
            int row = R + rt * 16 + q;
            row = row < N ? row : N - 1;
            bf16x8 a = *(const bf16x8*)(hs + (size_t)row * 128 + kc * 32 + g * 8);
#pragma unroll
            for (int c = 0; c < 4; ++c)
                acc[rt][c] = __builtin_amdgcn_mfma_f32_16x16x32_bf16(a, b[c], acc[rt][c], 0, 0, 0);
        }
    }
#pragma unroll
    for (int rt = 0; rt < 2; ++rt)
#pragma unroll
        for (int r = 0; r < 4; ++r) {
            int grow = R + rt * 16 + 4 * g + r;
            if (grow < N) {
                float wd = dinv[grow];
                unsigned short* orow = h2f + (size_t)grow * 32;
#pragma unroll
                for (int c = 0; c < 2; ++c)
                    orow[c * 16 + q] = pack8(acc[rt][c][r] * wd, acc[rt][c + 2][r] * wd);
            }
        }
}

// ---------------- layer-2 pull aggregation + log_softmax: lane-owns-slot ----------------
// h2f row = 16 u32 (64 B). 16-lane group per edge: lane q in [0,16) loads u32 slot q.
// u32 slot q = feats (2q, 2q+32, 2q+1, 2q+33). 4 groups take edge strides; 2-level combine.
__global__ __launch_bounds__(256) void agg2_ls_kernel(const uint32* __restrict__ h2,  // N x 16 u32
                                                      const float* __restrict__ dinv,
                                                      const int* __restrict__ srt,
                                                      const int* __restrict__ rowstart,
                                                      const int* __restrict__ rowend,
                                                      const float* __restrict__ bias,
                                                      float* __restrict__ out, int n) {
    int wid = (int)(((long)blockIdx.x * blockDim.x + threadIdx.x) >> 6);
    int lane = threadIdx.x & 63;
    if (wid >= n) return;
    int q = lane & 15;
    int g = lane >> 4;
    int start = rowstart[wid];
    int end = rowend[wid];
    f32x2 aL = {0.f, 0.f}, aH = {0.f, 0.f};  // aL=(f2q, f2q+32), aH=(f2q+1, f2q+33)
    if (g == 0) {  // self
        uint32 u = h2[(size_t)wid * 16 + q];
        aL = up8<false>(u); aH = up8<true>(u);
    }
    int e = start + g;
    for (; e + 12 < end; e += 16) {  // 4 edges in flight per group
        int s0 = srt[e], s1 = srt[e + 4], s2 = srt[e + 8], s3 = srt[e + 12];
        uint32 u0 = h2[(size_t)s0 * 16 + q];
        uint32 u1 = h2[(size_t)s1 * 16 + q];
        uint32 u2 = h2[(size_t)s2 * 16 + q];
        uint32 u3 = h2[(size_t)s3 * 16 + q];
        aL += up8<false>(u0); aH += up8<true>(u0);
        aL += up8<false>(u1); aH += up8<true>(u1);
        aL += up8<false>(u2); aH += up8<true>(u2);
        aL += up8<false>(u3); aH += up8<true>(u3);
    }
    for (; e < end; e += 4) {
        uint32 u = h2[(size_t)srt[e] * 16 + q];
        aL += up8<false>(u); aH += up8<true>(u);
    }
    aL += shflx(aL, 16); aH += shflx(aH, 16);
    aL += shflx(aL, 32); aH += shflx(aH, 32);
    float wd = dinv[wid];
    float2 b0 = ((const float2*)bias)[q];        // b[2q], b[2q+1]
    float2 b1 = ((const float2*)bias)[q + 16];   // b[2q+32], b[2q+33]
    float v0 = fmaf(wd, aL.x, b0.x);  // f2q
    float v1 = fmaf(wd, aH.x, b0.y);  // f2q+1
    float v2 = fmaf(wd, aL.y, b1.x);  // f2q+32
    float v3 = fmaf(wd, aH.y, b1.y);  // f2q+33
    float m = fmaxf(fmaxf(v0, v1), fmaxf(v2, v3));
#pragma unroll
    for (int o = 1; o <= 8; o <<= 1) m = fmaxf(m, __shfl_xor(m, o, WAVE));
    float s = __expf(v0 - m) + __expf(v1 - m) + __expf(v2 - m) + __expf(v3 - m);
#pragma unroll
    for (int o = 1; o <= 8; o <<= 1) s += __shfl_xor(s, o, WAVE);
    float lg = __logf(s) + m;
    if (g == 0) {
        *(float2*)&out[(size_t)wid * 64 + 2 * q] = make_float2(v0 - lg, v1 - lg);
        *(float2*)&out[(size_t)wid * 64 + 32 + 2 * q] = make_float2(v2 - lg, v3 - lg);
    }
}

extern "C" void kernel_launch(void* const* d_in, const int* in_sizes, int n_in,
                              void* d_out, int out_size, void* d_ws, size_t ws_size,
                              hipStream_t stream) {
    const float* x  = (const float*)d_in[0];
    const float* W1 = (const float*)d_in[1];
    const float* b1 = (const float*)d_in[2];
    const float* W2 = (const float*)d_in[3];
    const float* b2 = (const float*)d_in[4];
    const int* edge = (const int*)d_in[5];

    const int N = in_sizes[0] / 256;
    const int E = in_sizes[5] / 2;
    const int* src = edge;
    const int* dst = edge + E;

    const int NBUCK = (N + 511) >> 9;  // <=256
    int mean = E / NBUCK;
    int CAP = mean + (int)(8.5 * __builtin_sqrt((double)mean)) + 32;
    CAP = (CAP + 63) & ~63;
    if (CAP > 36864) CAP = 36864;  // LDS flush buffer bound (144 KB)

    // ws layout (4B units): gcnt[256] | w1f[16384] | w2f[4096] | dinv[N] | rowstart[N]
    //   | rowend[N] | sorted[NBUCK*CAP] | h1f[N*32] | h2f[N*16] | agg1bf[N*64] (pairs alias)
    int*    gcnt     = (int*)d_ws;
    uint32* w1f      = (uint32*)(gcnt + 256);
    uint32* w2f      = w1f + 16384;
    float*  dinv     = (float*)(w2f + 4096);
    int*    rowstart = (int*)(dinv + N);
    int*    rowend   = rowstart + N;
    int*    sorted   = rowend + N;
    uint32* h1f      = (uint32*)(sorted + (size_t)NBUCK * CAP);  // N x 32 u32 (fp8)
    uint32* h2f      = h1f + (size_t)N * 32;                     // N x 16 u32 (fp8)
    uint32* agg1bf   = h2f + (size_t)N * 16;
    uint32* pairs    = agg1bf;  // dead before agg1bf is written
    float*  outp     = (float*)d_out;

    const int TB = 256;

    // 0) weight conversion to fragment-ordered bf16 (+ zero gcnt)
    convert_w_kernel<<<80, TB, 0, stream>>>(W1, W2, w1f, w2f, gcnt);

    // 1) CSR build via two-pass bucket sort (also produces dinv)
    binsort_kernel<<<(E + BIN_EPB - 1) / BIN_EPB, BIN_TB, 0, stream>>>(src, dst, gcnt, pairs, E, CAP);
    bucket_csr_kernel<<<NBUCK, 1024, (size_t)CAP * 4, stream>>>(pairs, gcnt, sorted, rowstart, rowend, dinv, N, CAP);

    // 2) h1f = fp8(dinv * (x @ W1))  [MFMA]
    gemm1_mfma<<<(N + 127) / 128, TB, 0, stream>>>(x, w1f, dinv, (unsigned short*)h1f, N);

    // 3) agg1bf = bf16(relu(dinv[d]*(self+sum) + b1)), lane-owns-slot fp8 gather
    agg1_kernel<<<(N * 64 + TB - 1) / TB, TB, 0, stream>>>(h1f, dinv, sorted, rowstart, rowend, b1, agg1bf, N);

    // 4) h2f = fp8(dinv * (agg1 @ W2))  [MFMA, bf16 A direct]
    gemm2_mfma<<<(N + 127) / 128, TB, 0, stream>>>(agg1bf, w2f, dinv, (unsigned short*)h2f, N);

    // 5) out = log_softmax(dinv[d]*(self+sum) + b2), lane-owns-slot fp8 gather
    agg2_ls_kernel<<<(N * 64 + TB - 1) / TB, TB, 0, stream>>>(h2f, dinv, sorted, rowstart, rowend, b2, outp, N);
}